// Round 5
// baseline (1536.468 us; speedup 1.0000x reference)
//
#include <hip/hip_runtime.h>
#include <math.h>

// Problem constants
#define NSAMP 220500
#define NCH   28
#define L_GT  1000
#define L_ENV 2000
#define HPCH  24
#define TILE  2048
#define BLOCK 256

// Padded tap lengths: multiples of 48 (6-group macro-iteration, tap dbuf period 2)
#define LP_GT4 4032   // 3997 actual
#define LP_HP  1008
#define LP_ENV 2016
#define LP_SRC 288    // 256 actual
#define LP_LPF 144    // 133 actual

#define WTILE 512     // wave-private tile for env kernels
#define NT512 431     // ceil(NSAMP/512)

typedef __attribute__((ext_vector_type(4))) float f32x4;

// Stride-9 LDS layout (proven round 4): logical u -> u + (u>>3); aligned
// 8-blocks contiguous at phys 9b; per-lane stride 9 dwords (odd) -> <=2-way.
__device__ __forceinline__ int phys9(int u) { return u + (u >> 3); }

// 8 taps x 8 outputs, single channel, taps from registers.
// ASC=false (conv): out j, tap kp uses W[8+j-kp] (1..15); ASC=true: W[j+kp] (0..14)
template<bool ASC>
__device__ __forceinline__ void group8r(const float (&LO)[8], const float (&HI)[8],
                                        float (&acc)[8], const f32x4 (&T)[2])
{
#pragma unroll
    for (int kp = 0; kp < 8; kp++) {
        const float hk = T[kp >> 2][kp & 3];
#pragma unroll
        for (int j = 0; j < 8; j++) {
            const int m = ASC ? (j + kp) : (8 + j - kp);
            const float w = (m < 8) ? LO[m] : HI[m - 8];
            acc[j] = fmaf(hk, w, acc[j]);
        }
    }
}

// 8 taps x 8 outputs x 4 channels (desc only), shared window
__device__ __forceinline__ void group8x4(const float (&LO)[8], const float (&HI)[8],
                                         float (&acc)[4][8], const f32x4 (&T)[4][2])
{
#pragma unroll
    for (int kp = 0; kp < 8; kp++) {
#pragma unroll
        for (int cc = 0; cc < 4; cc++) {
            const float hk = T[cc][kp >> 2][kp & 3];
#pragma unroll
            for (int j = 0; j < 8; j++) {
                const int m = 8 + j - kp;
                const float w = (m < 8) ? LO[m] : HI[m - 8];
                acc[cc][j] = fmaf(hk, w, acc[cc][j]);
            }
        }
    }
}

// ---------------------------------------------------------------------------
// Gammatone^4: 4 channels per block share one staged x window.
// y[c,n] = sum_k h4[c,k] x[n-k].  grid (108, 7), 256 thr, RPT=8.
// ---------------------------------------------------------------------------
__global__ __launch_bounds__(BLOCK, 3)
void fir_gt4(const float* __restrict__ xin, const float* __restrict__ taps,
             float* __restrict__ out)
{
    extern __shared__ float s[];
    const int n0 = blockIdx.x * TILE;
    const int c0 = blockIdx.y * 4;
    constexpr int Lpad = LP_GT4;

    constexpr int E = TILE + Lpad - 1;
    for (int i = threadIdx.x; i < E; i += BLOCK) {
        int p = n0 - (Lpad - 1) + i;
        s[phys9(i + 9)] = (p >= 0 && p < NSAMP) ? xin[p] : 0.f;
    }
    __syncthreads();

    const int t = threadIdx.x;
    constexpr int LB = Lpad / 8;
    const int B = 9 * (t + LB);

    const f32x4* tv[4];
#pragma unroll
    for (int cc = 0; cc < 4; cc++)
        tv[cc] = (const f32x4*)(taps + (long)(c0 + cc) * Lpad);

    float Ab[8], Bb[8], Cb[8];
    float acc[4][8];
#pragma unroll
    for (int cc = 0; cc < 4; cc++)
#pragma unroll
        for (int j = 0; j < 8; j++) acc[cc][j] = 0.f;
#pragma unroll
    for (int m = 0; m < 8; m++) Ab[m] = s[B + m];
#pragma unroll
    for (int m = 0; m < 8; m++) Bb[m] = s[B + 9 + m];

    f32x4 TA[4][2], TB[4][2];
#pragma unroll
    for (int cc = 0; cc < 4; cc++) { TA[cc][0] = tv[cc][0]; TA[cc][1] = tv[cc][1]; }

    int Mb = B - 54;                       // biased macro base (offsets 0..45)
    constexpr int NIT6 = Lpad / 48;        // 84
#pragma unroll 1
    for (int im = 0; im < NIT6; ++im) {
        const float* p = s + Mb;
        // slot0 g=6im+0: consume (Ab,Bb)/TA; pf Cb<-blk q0-1; TB<-taps g+1
#pragma unroll
        for (int m = 0; m < 8; m++) Cb[m] = p[45 + m];
#pragma unroll
        for (int cc = 0; cc < 4; cc++) { TB[cc][0] = tv[cc][2];  TB[cc][1] = tv[cc][3]; }
        group8x4(Ab, Bb, acc, TA);
        // slot1: consume (Cb,Ab)/TB; pf Bb; TA<-taps g+2
#pragma unroll
        for (int m = 0; m < 8; m++) Bb[m] = p[36 + m];
#pragma unroll
        for (int cc = 0; cc < 4; cc++) { TA[cc][0] = tv[cc][4];  TA[cc][1] = tv[cc][5]; }
        group8x4(Cb, Ab, acc, TB);
        // slot2: consume (Bb,Cb)/TA; pf Ab; TB<-taps g+3
#pragma unroll
        for (int m = 0; m < 8; m++) Ab[m] = p[27 + m];
#pragma unroll
        for (int cc = 0; cc < 4; cc++) { TB[cc][0] = tv[cc][6];  TB[cc][1] = tv[cc][7]; }
        group8x4(Bb, Cb, acc, TA);
        // slot3: consume (Ab,Bb)/TB; pf Cb; TA<-taps g+4
#pragma unroll
        for (int m = 0; m < 8; m++) Cb[m] = p[18 + m];
#pragma unroll
        for (int cc = 0; cc < 4; cc++) { TA[cc][0] = tv[cc][8];  TA[cc][1] = tv[cc][9]; }
        group8x4(Ab, Bb, acc, TB);
        // slot4: consume (Cb,Ab)/TA; pf Bb; TB<-taps g+5
#pragma unroll
        for (int m = 0; m < 8; m++) Bb[m] = p[9 + m];
#pragma unroll
        for (int cc = 0; cc < 4; cc++) { TB[cc][0] = tv[cc][10]; TB[cc][1] = tv[cc][11]; }
        group8x4(Cb, Ab, acc, TA);
        // slot5: consume (Bb,Cb)/TB; pf Ab; TA<-taps g+6
#pragma unroll
        for (int m = 0; m < 8; m++) Ab[m] = p[0 + m];
#pragma unroll
        for (int cc = 0; cc < 4; cc++) { TA[cc][0] = tv[cc][12]; TA[cc][1] = tv[cc][13]; }
        group8x4(Bb, Cb, acc, TB);
        Mb -= 54;
#pragma unroll
        for (int cc = 0; cc < 4; cc++) tv[cc] += 12;
    }

    const int nb = n0 + 8 * t;
#pragma unroll
    for (int cc = 0; cc < 4; cc++) {
        float* y = out + (long)(c0 + cc) * NSAMP;
#pragma unroll
        for (int j = 0; j < 8; j++)
            if (nb + j < NSAMP) y[nb + j] = acc[cc][j];
    }
}

// ---------------------------------------------------------------------------
// Block-level causal FIR (src_fwd / HP / src_bwd / lpf), RPT=8, tap prefetch.
// ---------------------------------------------------------------------------
template<int Lpad, bool DELAYED>
__global__ __launch_bounds__(BLOCK)
void fir_blk(const float* __restrict__ in, long instride,
             const float* __restrict__ taps, int tapstride,
             float* __restrict__ out, long ostride,
             const int* __restrict__ delays, int chan0)
{
    extern __shared__ float s[];
    const int c  = blockIdx.y;
    const int n0 = blockIdx.x * TILE;
    const float* __restrict__ xin = in + (long)c * instride;
    float* __restrict__ y         = out + (long)c * ostride;
    int d = 0;
    if (DELAYED) d = delays[chan0 + c];

    constexpr int E = TILE + Lpad - 1;
    for (int i = threadIdx.x; i < E; i += BLOCK) {
        int p = n0 - (Lpad - 1) + i;
        float v = 0.f;
        if (p >= 0 && p < NSAMP) {
            int q = p + d;
            if (!DELAYED || q < NSAMP) v = xin[q];
        }
        s[phys9(i + 9)] = v;
    }
    __syncthreads();

    const int t = threadIdx.x;
    constexpr int LB = Lpad / 8;
    const int B = 9 * (t + LB);
    const f32x4* tv = (const f32x4*)(taps + (long)c * tapstride);

    float Ab[8], Bb[8], Cb[8];
    float acc[8] = {0,0,0,0,0,0,0,0};
#pragma unroll
    for (int m = 0; m < 8; m++) Ab[m] = s[B + m];
#pragma unroll
    for (int m = 0; m < 8; m++) Bb[m] = s[B + 9 + m];
    f32x4 TA[2], TB[2];
    TA[0] = tv[0]; TA[1] = tv[1];

    int Mb = B - 54;
    constexpr int NIT6 = Lpad / 48;
#pragma unroll 1
    for (int im = 0; im < NIT6; ++im) {
        const float* p = s + Mb;
#pragma unroll
        for (int m = 0; m < 8; m++) Cb[m] = p[45 + m];
        TB[0] = tv[2];  TB[1] = tv[3];
        group8r<false>(Ab, Bb, acc, TA);
#pragma unroll
        for (int m = 0; m < 8; m++) Bb[m] = p[36 + m];
        TA[0] = tv[4];  TA[1] = tv[5];
        group8r<false>(Cb, Ab, acc, TB);
#pragma unroll
        for (int m = 0; m < 8; m++) Ab[m] = p[27 + m];
        TB[0] = tv[6];  TB[1] = tv[7];
        group8r<false>(Bb, Cb, acc, TA);
#pragma unroll
        for (int m = 0; m < 8; m++) Cb[m] = p[18 + m];
        TA[0] = tv[8];  TA[1] = tv[9];
        group8r<false>(Ab, Bb, acc, TB);
#pragma unroll
        for (int m = 0; m < 8; m++) Bb[m] = p[9 + m];
        TB[0] = tv[10]; TB[1] = tv[11];
        group8r<false>(Cb, Ab, acc, TA);
#pragma unroll
        for (int m = 0; m < 8; m++) Ab[m] = p[0 + m];
        TA[0] = tv[12]; TA[1] = tv[13];
        group8r<false>(Bb, Cb, acc, TB);
        Mb -= 54;
        tv += 12;
    }

    const int nb = n0 + 8 * t;
#pragma unroll
    for (int j = 0; j < 8; j++)
        if (nb + j < NSAMP) y[nb + j] = acc[j];
}

// ---------------------------------------------------------------------------
// env_f: wave-private 512-tile causal FIR of |pass_del| (desc), tap prefetch.
// gw = blockIdx.x*4 + wid; c = gw/431, n0w = (gw%431)*512.
// ---------------------------------------------------------------------------
#define ESLICE 2880   // floats per wave slice (covers phys9(2535)+margin)

__global__ __launch_bounds__(BLOCK)
void env_fwd(const float* __restrict__ in, const float* __restrict__ taps,
             float* __restrict__ out)
{
    extern __shared__ float S[];
    const int wid  = threadIdx.x >> 6;
    const int lane = threadIdx.x & 63;
    float* s = S + wid * ESLICE;
    const int gw  = blockIdx.x * 4 + wid;
    const int c   = gw / NT512;
    const int n0w = (gw % NT512) * WTILE;
    constexpr int Lpad = LP_ENV;
    const float* __restrict__ xin = in + (long)c * NSAMP;

    constexpr int E = WTILE + Lpad - 1;    // 2527
    for (int i = lane; i < E; i += 64) {
        int p = n0w - (Lpad - 1) + i;
        s[phys9(i + 9)] = (p >= 0 && p < NSAMP) ? fabsf(xin[p]) : 0.f;
    }
    __syncthreads();

    constexpr int LB = Lpad / 8;           // 252
    const int B = 9 * (lane + LB);
    const f32x4* tv = (const f32x4*)(taps + (long)c * Lpad);

    float Ab[8], Bb[8], Cb[8];
    float acc[8] = {0,0,0,0,0,0,0,0};
#pragma unroll
    for (int m = 0; m < 8; m++) Ab[m] = s[B + m];
#pragma unroll
    for (int m = 0; m < 8; m++) Bb[m] = s[B + 9 + m];
    f32x4 TA[2], TB[2];
    TA[0] = tv[0]; TA[1] = tv[1];

    int Mb = B - 54;
    constexpr int NIT6 = Lpad / 48;        // 42
#pragma unroll 1
    for (int im = 0; im < NIT6; ++im) {
        const float* p = s + Mb;
#pragma unroll
        for (int m = 0; m < 8; m++) Cb[m] = p[45 + m];
        TB[0] = tv[2];  TB[1] = tv[3];
        group8r<false>(Ab, Bb, acc, TA);
#pragma unroll
        for (int m = 0; m < 8; m++) Bb[m] = p[36 + m];
        TA[0] = tv[4];  TA[1] = tv[5];
        group8r<false>(Cb, Ab, acc, TB);
#pragma unroll
        for (int m = 0; m < 8; m++) Ab[m] = p[27 + m];
        TB[0] = tv[6];  TB[1] = tv[7];
        group8r<false>(Bb, Cb, acc, TA);
#pragma unroll
        for (int m = 0; m < 8; m++) Cb[m] = p[18 + m];
        TA[0] = tv[8];  TA[1] = tv[9];
        group8r<false>(Ab, Bb, acc, TB);
#pragma unroll
        for (int m = 0; m < 8; m++) Bb[m] = p[9 + m];
        TB[0] = tv[10]; TB[1] = tv[11];
        group8r<false>(Cb, Ab, acc, TA);
#pragma unroll
        for (int m = 0; m < 8; m++) Ab[m] = p[0 + m];
        TA[0] = tv[12]; TA[1] = tv[13];
        group8r<false>(Bb, Cb, acc, TB);
        Mb -= 54;
        tv += 12;
    }

    float* y = out + (long)c * NSAMP;
    const int nb = n0w + 8 * lane;
#pragma unroll
    for (int j = 0; j < 8; j++)
        if (nb + j < NSAMP) y[nb + j] = acc[j];
}

// ---------------------------------------------------------------------------
// env backward (asc) + recruitment gain, wave-private 512-tile, tap prefetch.
// env[n] = sum_k h[k]|envf[n+k]|; pc[n] *= gain(env[n]) in place.
// ---------------------------------------------------------------------------
__global__ __launch_bounds__(BLOCK)
void env_bwd_gain(const float* __restrict__ envf, const float* __restrict__ taps,
                  float* __restrict__ pc,
                  const float* __restrict__ ratios, const float* __restrict__ eqloud)
{
    extern __shared__ float S[];
    const int wid  = threadIdx.x >> 6;
    const int lane = threadIdx.x & 63;
    float* s = S + wid * ESLICE;
    const int gw  = blockIdx.x * 4 + wid;
    const int c   = gw / NT512;
    const int n0w = (gw % NT512) * WTILE;
    constexpr int Lpad = LP_ENV;
    const float* __restrict__ xin = envf + (long)c * NSAMP;

    constexpr int E2 = WTILE + Lpad + 8;   // 2536
    for (int i = lane; i < E2; i += 64) {
        int p = n0w + i;
        s[phys9(i)] = (p < NSAMP) ? fabsf(xin[p]) : 0.f;
    }
    __syncthreads();

    const f32x4* tv = (const f32x4*)(taps + (long)c * Lpad);
    float Ab[8], Bb[8], Cb[8];
    float acc[8] = {0,0,0,0,0,0,0,0};
#pragma unroll
    for (int m = 0; m < 8; m++) Ab[m] = s[9 * lane + m];
#pragma unroll
    for (int m = 0; m < 8; m++) Bb[m] = s[9 * lane + 9 + m];
    f32x4 TA[2], TB[2];
    TA[0] = tv[0]; TA[1] = tv[1];

    int Mb = 9 * lane;
    constexpr int NIT6 = Lpad / 48;
#pragma unroll 1
    for (int im = 0; im < NIT6; ++im) {
        const float* p = s + Mb;
#pragma unroll
        for (int m = 0; m < 8; m++) Cb[m] = p[18 + m];
        TB[0] = tv[2];  TB[1] = tv[3];
        group8r<true>(Ab, Bb, acc, TA);
#pragma unroll
        for (int m = 0; m < 8; m++) Ab[m] = p[27 + m];
        TA[0] = tv[4];  TA[1] = tv[5];
        group8r<true>(Bb, Cb, acc, TB);
#pragma unroll
        for (int m = 0; m < 8; m++) Bb[m] = p[36 + m];
        TB[0] = tv[6];  TB[1] = tv[7];
        group8r<true>(Cb, Ab, acc, TA);
#pragma unroll
        for (int m = 0; m < 8; m++) Cb[m] = p[45 + m];
        TA[0] = tv[8];  TA[1] = tv[9];
        group8r<true>(Ab, Bb, acc, TB);
#pragma unroll
        for (int m = 0; m < 8; m++) Ab[m] = p[54 + m];
        TB[0] = tv[10]; TB[1] = tv[11];
        group8r<true>(Bb, Cb, acc, TA);
#pragma unroll
        for (int m = 0; m < 8; m++) Bb[m] = p[63 + m];
        TA[0] = tv[12]; TA[1] = tv[13];
        group8r<true>(Cb, Ab, acc, TB);
        Mb += 54;
        tv += 12;
    }

    const float emax = exp10f(0.05f * (eqloud[c] - 100.0f));
    const float er   = fmaxf(ratios[c], -5.0f) - 1.0f;
    const int nb = n0w + 8 * lane;
#pragma unroll
    for (int j = 0; j < 8; j++) {
        int n = nb + j;
        if (n < NSAMP) {
            float env = acc[j];
            float ecl = fminf(fmaxf(env, 1e-9f), emax);
            float enr = fmaxf(ecl / emax, 1e-6f);
            float g   = fminf(powf(enr, er), 100.0f);
            long id = (long)c * NSAMP + n;
            pc[id] = pc[id] * g;
        }
    }
}

// out[c,m] = sum_k a[c,k] a[c,m-k]; zeros for m in [Mlen, Mpad)
__global__ void conv_self(const float* __restrict__ a, int astride, int La,
                          float* __restrict__ out, int ostride, int Mlen, int Mpad)
{
    extern __shared__ float s[];
    const int c = blockIdx.y;
    const float* __restrict__ ar = a + (long)c * astride;
    for (int i = threadIdx.x; i < La; i += blockDim.x) s[i] = ar[i];
    __syncthreads();
    int m = blockIdx.x * blockDim.x + threadIdx.x;
    float acc = 0.f;
    for (int k = 0; k < La; k++) {
        int mi = m - k;
        float bv = ((unsigned)mi < (unsigned)La) ? s[mi] : 0.f;
        acc = fmaf(s[k], bv, acc);
    }
    if (m < Mpad) out[(long)c * ostride + m] = (m < Mlen) ? acc : 0.f;
}

__global__ void pad_copy(const float* __restrict__ src, int L, int sstride,
                         float* __restrict__ dst, int Lpad)
{
    int c = blockIdx.y;
    int k = blockIdx.x * blockDim.x + threadIdx.x;
    if (k < Lpad) dst[(long)c * Lpad + k] = (k < L) ? src[(long)c * sstride + k] : 0.f;
}

__global__ void delay_copy(const float* __restrict__ a, float* __restrict__ b,
                           const int* __restrict__ delays)
{
    int c = blockIdx.y;
    int n = blockIdx.x * blockDim.x + threadIdx.x;
    if (n < NSAMP) {
        int q = n + delays[c];
        b[(long)c * NSAMP + n] = (q < NSAMP) ? a[(long)c * NSAMP + q] : 0.f;
    }
}

__global__ void reduce_coch(const float* __restrict__ b, float* __restrict__ coch)
{
    int n = blockIdx.x * blockDim.x + threadIdx.x;
    if (n < NSAMP) {
        float sum = 0.f;
        for (int c = 0; c < NCH; c++) sum += b[(long)c * NSAMP + n];
        coch[n] = sum * 0.31622776601683794f;
    }
}

static inline size_t lds_blk(int Lpad)
{
    int umax = TILE + Lpad + 8;
    return (size_t)(umax + (umax >> 3) + 16) * 4;
}

extern "C" void kernel_launch(void* const* d_in, const int* in_sizes, int n_in,
                              void* d_out, int out_size, void* d_ws, size_t ws_size,
                              hipStream_t stream)
{
    const float* x       = (const float*)d_in[0];
    const float* src_fwd = (const float*)d_in[1];
    const float* src_bwd = (const float*)d_in[2];
    const float* lpf     = (const float*)d_in[3];
    const float* gtn     = (const float*)d_in[4];  // [28,1000]
    const float* hp      = (const float*)d_in[5];  // [24,1000]
    const float* clpf    = (const float*)d_in[6];  // [28,2000]
    const float* ratios  = (const float*)d_in[7];
    const float* eqloud  = (const float*)d_in[8];
    const int*   delays  = (const int*)d_in[9];
    float* out = (float*)d_out;

    float* ws   = (float*)d_ws;
    const size_t CNs = (size_t)NCH * NSAMP;
    float* bufA  = ws;                           // C*N (y4, then env_f)
    float* bufB  = bufA + CNs;                   // C*N (pass_del -> coch_c)
    float* xc    = bufB + CNs;                   // N
    float* coch  = xc + NSAMP;                   // N
    float* t1    = coch + NSAMP;                 // N
    float* h2    = t1 + NSAMP;                   // 28*2000
    float* h4    = h2 + (size_t)NCH * 2000;      // 28*LP_GT4
    float* hpP   = h4 + (size_t)NCH * LP_GT4;    // 24*LP_HP
    float* clpfP = hpP + (size_t)HPCH * LP_HP;   // 28*LP_ENV
    float* sfP   = clpfP + (size_t)NCH * LP_ENV; // LP_SRC
    float* sbP   = sfP + LP_SRC;                 // LP_SRC
    float* lpP   = sbP + LP_SRC;                 // LP_LPF (+ tail slack in ws)

    dim3 blk(BLOCK);
    const int NT = (NSAMP + TILE - 1) / TILE;    // 108
    const int EGRID = (NT512 * NCH) / 4;         // 3017 blocks (4 waves each)

    // --- filter prep ---
    conv_self<<<dim3(8, NCH), blk, L_GT * 4, stream>>>(
        gtn, L_GT, L_GT, h2, 2000, 1999, 1999);
    conv_self<<<dim3((LP_GT4 + BLOCK - 1) / BLOCK, NCH), blk, 1999 * 4, stream>>>(
        h2, 2000, 1999, h4, LP_GT4, 3997, LP_GT4);
    pad_copy<<<dim3(4, HPCH), blk, 0, stream>>>(hp, L_GT, L_GT, hpP, LP_HP);
    pad_copy<<<dim3(8, NCH), blk, 0, stream>>>(clpf, L_ENV, L_ENV, clpfP, LP_ENV);
    pad_copy<<<dim3(2, 1), blk, 0, stream>>>(src_fwd, 256, 256, sfP, LP_SRC);
    pad_copy<<<dim3(2, 1), blk, 0, stream>>>(src_bwd, 256, 256, sbP, LP_SRC);
    pad_copy<<<dim3(1, 1), blk, 0, stream>>>(lpf, 133, 133, lpP, LP_LPF);

    // --- signal path ---
    // xc = fir1(x, src_fwd)
    fir_blk<LP_SRC, false><<<dim3(NT, 1), blk, lds_blk(LP_SRC), stream>>>(
        x, 0, sfP, LP_SRC, xc, 0, nullptr, 0);

    // y4 = gammatone^4 (collapsed), 4 channels/block
    fir_gt4<<<dim3(NT, 7), blk, lds_blk(LP_GT4), stream>>>(xc, h4, bufA);

    // pass_del ch 0..3: delayed copy
    delay_copy<<<dim3((NSAMP + BLOCK - 1) / BLOCK, 4), blk, 0, stream>>>(bufA, bufB, delays);

    // pass_del ch 4..27: HP FIR with delay at input fetch
    fir_blk<LP_HP, true><<<dim3(NT, HPCH), blk, lds_blk(LP_HP), stream>>>(
        bufA + 4 * (size_t)NSAMP, NSAMP, hpP, LP_HP,
        bufB + 4 * (size_t)NSAMP, NSAMP, delays, 4);

    // env_f = fir(|pass_del|, chan_lpf)   (wave-tiled)
    env_fwd<<<dim3(EGRID), blk, 4 * ESLICE * 4, stream>>>(bufB, clpfP, bufA);

    // env (anti-causal) + recruitment gain  (wave-tiled)
    env_bwd_gain<<<dim3(EGRID), blk, 4 * ESLICE * 4, stream>>>(
        bufA, clpfP, bufB, ratios, eqloud);

    // coch = 10^-0.5 * sum_c coch_c
    reduce_coch<<<dim3((NSAMP + BLOCK - 1) / BLOCK), blk, 0, stream>>>(bufB, coch);

    // out = fir1(fir1(coch, src_bwd), lpf)
    fir_blk<LP_SRC, false><<<dim3(NT, 1), blk, lds_blk(LP_SRC), stream>>>(
        coch, 0, sbP, LP_SRC, t1, 0, nullptr, 0);
    fir_blk<LP_LPF, false><<<dim3(NT, 1), blk, lds_blk(LP_LPF), stream>>>(
        t1, 0, lpP, LP_LPF, out, 0, nullptr, 0);
}

// Round 6
// 1174.272 us; speedup vs baseline: 1.3084x; 1.3084x over previous
//
#include <hip/hip_runtime.h>
#include <math.h>

// Problem constants
#define NSAMP 220500
#define NCH   28
#define L_GT  1000
#define L_ENV 2000
#define HPCH  24
#define TILE  2048
#define BLOCK 256

// Padded tap lengths
#define LP_GT4 4032   // 3997 actual, 126 K-blocks of 32
#define LP_HP  1008
#define LP_ENV 2016
#define LP_SRC 288
#define LP_LPF 144

#define WTILE 512
#define NT512 431     // ceil(NSAMP/512)

// gt4 MFMA geometry
#define GTBLK  256                      // samples per block (4 waves x 64)
#define GTGRID 862                      // ceil(NSAMP/256)
#define EWIN   4288                     // staged window elements
#define VPITCH 2160                     // dwords per parity array
#define KSTEPS 126                      // 4032/32

typedef __attribute__((ext_vector_type(4))) float f32x4;
typedef __attribute__((ext_vector_type(8))) short bf16x8;

__device__ __forceinline__ int phys9(int u) { return u + (u >> 3); }

__device__ __forceinline__ unsigned short f2bf(float x) {
    unsigned u = __float_as_uint(x);
    u += 0x7FFFu + ((u >> 16) & 1u);
    return (unsigned short)(u >> 16);
}

// ===========================================================================
// Gammatone^4 via MFMA Toeplitz GEMM.
// Y[m][j] = sum_k H[m][k] X[nb+j-k]; per K-block c (kk=32c+K'), K'-reversed:
//   A'_c[m][K'] = H[m][32c+31-K']   (prep'd, fragment-ordered, bf16 hi+lo)
//   B_c[K'][j]  = Xh[nb + j - 32c - 31 + K']
// Fragment maps (gfx950 16x16x32 bf16): A: m=l&15, K'=8(l>>4)+i;
// B: n=l&15, K'=8(l>>4)+i; D: col=l&15, row=4(l>>4)+reg.
// ===========================================================================
__global__ void frag_taps(const float* __restrict__ h4, unsigned short* __restrict__ TF)
{
    const int c    = blockIdx.x;          // K-step
    const int lane = threadIdx.x & 63;
    const int wv   = threadIdx.x >> 6;
    const int s    = wv >> 1;             // 0=hh 1=hl
    const int mt   = wv & 1;              // M-tile
    const int chan = mt * 16 + (lane & 15);
    unsigned short* dst = TF + (size_t)s * 129024 + (size_t)c * 1024 + mt * 512 + lane * 8;
#pragma unroll
    for (int i = 0; i < 8; i++) {
        int k = 32 * c + 31 - 8 * (lane >> 4) - i;
        float val = (chan < NCH) ? h4[(size_t)chan * LP_GT4 + k] : 0.f;
        unsigned short hh = f2bf(val);
        float fhh = __uint_as_float((unsigned)hh << 16);
        unsigned short hl = f2bf(val - fhh);
        dst[i] = s ? hl : hh;
    }
}

#define MFMA32 __builtin_amdgcn_mfma_f32_16x16x32_bf16

__global__ __launch_bounds__(BLOCK)
void gt4_mfma(const float* __restrict__ xc, const unsigned short* __restrict__ TF,
              float* __restrict__ out)
{
    extern __shared__ float S[];
    const int NB   = blockIdx.x * GTBLK;
    const int lane = threadIdx.x & 63;
    const int w    = threadIdx.x >> 6;

    // ---- stage window as bf16 even/odd dword-pair arrays ----
    unsigned short* we2 = (unsigned short*)S;             // We[v]=(x[2v],x[2v+1])
    unsigned short* wo2 = (unsigned short*)(S + VPITCH);  // Wo[v]=(x[2v+1],x[2v+2])
    for (int e = threadIdx.x; e < EWIN; e += BLOCK) {
        int p = NB - 4031 + e;
        float v = (p >= 0 && p < NSAMP) ? xc[p] : 0.f;
        unsigned short h = f2bf(v);
        we2[e] = h;
        if (e >= 1) wo2[e - 1] = h;
    }
    __syncthreads();

    // lane-parity array select; v = (S0>>1) + 8*jt - 16*c
    const int S0 = 4000 + 64 * w + (lane & 15) + 8 * (lane >> 4);
    const float* arrp = (S0 & 1) ? (S + VPITCH) : S;
    const int vb0 = S0 >> 1;

    const unsigned short* tp = TF + lane * 8;   // + s*129024 + c*1024 + mt*512

    f32x4 a00 = {0,0,0,0}, a01 = {0,0,0,0}, a02 = {0,0,0,0}, a03 = {0,0,0,0};
    f32x4 a10 = {0,0,0,0}, a11 = {0,0,0,0}, a12 = {0,0,0,0}, a13 = {0,0,0,0};

    bf16x8 Ah0, Ah1, Al0, Al1;   // A-set (even c)
    bf16x8 Bh0, Bh1, Bl0, Bl1;   // B-set (odd c)

#define LOADA(H0,H1,L0,L1,cc_) { \
    H0 = *(const bf16x8*)(tp + (size_t)(cc_) * 1024);            \
    H1 = *(const bf16x8*)(tp + (size_t)(cc_) * 1024 + 512);      \
    L0 = *(const bf16x8*)(tp + 129024 + (size_t)(cc_) * 1024);       \
    L1 = *(const bf16x8*)(tp + 129024 + (size_t)(cc_) * 1024 + 512); }

#define STEPC(H0,H1,L0,L1,vcc) { \
    union { float f[4]; bf16x8 v; } b0, b1, b2, b3;                          \
    b0.f[0]=arrp[(vcc)];    b0.f[1]=arrp[(vcc)+1];  b0.f[2]=arrp[(vcc)+2];  b0.f[3]=arrp[(vcc)+3];  \
    b1.f[0]=arrp[(vcc)+8];  b1.f[1]=arrp[(vcc)+9];  b1.f[2]=arrp[(vcc)+10]; b1.f[3]=arrp[(vcc)+11]; \
    b2.f[0]=arrp[(vcc)+16]; b2.f[1]=arrp[(vcc)+17]; b2.f[2]=arrp[(vcc)+18]; b2.f[3]=arrp[(vcc)+19]; \
    b3.f[0]=arrp[(vcc)+24]; b3.f[1]=arrp[(vcc)+25]; b3.f[2]=arrp[(vcc)+26]; b3.f[3]=arrp[(vcc)+27]; \
    a00 = MFMA32(H0, b0.v, a00, 0,0,0);  a00 = MFMA32(L0, b0.v, a00, 0,0,0); \
    a10 = MFMA32(H1, b0.v, a10, 0,0,0);  a10 = MFMA32(L1, b0.v, a10, 0,0,0); \
    a01 = MFMA32(H0, b1.v, a01, 0,0,0);  a01 = MFMA32(L0, b1.v, a01, 0,0,0); \
    a11 = MFMA32(H1, b1.v, a11, 0,0,0);  a11 = MFMA32(L1, b1.v, a11, 0,0,0); \
    a02 = MFMA32(H0, b2.v, a02, 0,0,0);  a02 = MFMA32(L0, b2.v, a02, 0,0,0); \
    a12 = MFMA32(H1, b2.v, a12, 0,0,0);  a12 = MFMA32(L1, b2.v, a12, 0,0,0); \
    a03 = MFMA32(H0, b3.v, a03, 0,0,0);  a03 = MFMA32(L0, b3.v, a03, 0,0,0); \
    a13 = MFMA32(H1, b3.v, a13, 0,0,0);  a13 = MFMA32(L1, b3.v, a13, 0,0,0); }

    LOADA(Ah0, Ah1, Al0, Al1, 0);
    int vc = vb0;
#pragma unroll 1
    for (int cc = 0; cc < KSTEPS / 2; ++cc) {
        LOADA(Bh0, Bh1, Bl0, Bl1, 2 * cc + 1);
        STEPC(Ah0, Ah1, Al0, Al1, vc);
        if (cc < KSTEPS / 2 - 1) LOADA(Ah0, Ah1, Al0, Al1, 2 * cc + 2);
        STEPC(Bh0, Bh1, Bl0, Bl1, vc - 16);
        vc -= 32;
    }
#undef STEPC
#undef LOADA

    // ---- store: D col=lane&15 (sample), row=4*(lane>>4)+r (channel) ----
    const int nbase = NB + 64 * w + (lane & 15);
    const int rbase = (lane >> 4) << 2;
#define STORE(ACC, mt_, jt_) { \
    int n = nbase + 16 * (jt_);                                              \
    if (n < NSAMP) {                                                         \
        _Pragma("unroll")                                                    \
        for (int r = 0; r < 4; r++) {                                        \
            int chan = (mt_) * 16 + rbase + r;                               \
            if (chan < NCH) out[(size_t)chan * NSAMP + n] = ACC[r];          \
        }                                                                    \
    } }
    STORE(a00, 0, 0) STORE(a01, 0, 1) STORE(a02, 0, 2) STORE(a03, 0, 3)
    STORE(a10, 1, 0) STORE(a11, 1, 1) STORE(a12, 1, 2) STORE(a13, 1, 3)
#undef STORE
}

// ===========================================================================
// VALU FIR machinery (proven rounds 4-5) for src/HP/env stages
// ===========================================================================
template<bool ASC>
__device__ __forceinline__ void group8r(const float (&LO)[8], const float (&HI)[8],
                                        float (&acc)[8], const f32x4 (&T)[2])
{
#pragma unroll
    for (int kp = 0; kp < 8; kp++) {
        const float hk = T[kp >> 2][kp & 3];
#pragma unroll
        for (int j = 0; j < 8; j++) {
            const int m = ASC ? (j + kp) : (8 + j - kp);
            const float w = (m < 8) ? LO[m] : HI[m - 8];
            acc[j] = fmaf(hk, w, acc[j]);
        }
    }
}

template<int Lpad, bool DELAYED>
__global__ __launch_bounds__(BLOCK)
void fir_blk(const float* __restrict__ in, long instride,
             const float* __restrict__ taps, int tapstride,
             float* __restrict__ out, long ostride,
             const int* __restrict__ delays, int chan0)
{
    extern __shared__ float s[];
    const int c  = blockIdx.y;
    const int n0 = blockIdx.x * TILE;
    const float* __restrict__ xin = in + (long)c * instride;
    float* __restrict__ y         = out + (long)c * ostride;
    int d = 0;
    if (DELAYED) d = delays[chan0 + c];

    constexpr int E = TILE + Lpad - 1;
    for (int i = threadIdx.x; i < E; i += BLOCK) {
        int p = n0 - (Lpad - 1) + i;
        float v = 0.f;
        if (p >= 0 && p < NSAMP) {
            int q = p + d;
            if (!DELAYED || q < NSAMP) v = xin[q];
        }
        s[phys9(i + 9)] = v;
    }
    __syncthreads();

    const int t = threadIdx.x;
    constexpr int LB = Lpad / 8;
    const int B = 9 * (t + LB);
    const f32x4* tv = (const f32x4*)(taps + (long)c * tapstride);

    float Ab[8], Bb[8], Cb[8];
    float acc[8] = {0,0,0,0,0,0,0,0};
#pragma unroll
    for (int m = 0; m < 8; m++) Ab[m] = s[B + m];
#pragma unroll
    for (int m = 0; m < 8; m++) Bb[m] = s[B + 9 + m];
    f32x4 TA[2], TB[2];
    TA[0] = tv[0]; TA[1] = tv[1];

    int Mb = B - 54;
    constexpr int NIT6 = Lpad / 48;
#pragma unroll 1
    for (int im = 0; im < NIT6; ++im) {
        const float* p = s + Mb;
#pragma unroll
        for (int m = 0; m < 8; m++) Cb[m] = p[45 + m];
        TB[0] = tv[2];  TB[1] = tv[3];
        group8r<false>(Ab, Bb, acc, TA);
#pragma unroll
        for (int m = 0; m < 8; m++) Bb[m] = p[36 + m];
        TA[0] = tv[4];  TA[1] = tv[5];
        group8r<false>(Cb, Ab, acc, TB);
#pragma unroll
        for (int m = 0; m < 8; m++) Ab[m] = p[27 + m];
        TB[0] = tv[6];  TB[1] = tv[7];
        group8r<false>(Bb, Cb, acc, TA);
#pragma unroll
        for (int m = 0; m < 8; m++) Cb[m] = p[18 + m];
        TA[0] = tv[8];  TA[1] = tv[9];
        group8r<false>(Ab, Bb, acc, TB);
#pragma unroll
        for (int m = 0; m < 8; m++) Bb[m] = p[9 + m];
        TB[0] = tv[10]; TB[1] = tv[11];
        group8r<false>(Cb, Ab, acc, TA);
#pragma unroll
        for (int m = 0; m < 8; m++) Ab[m] = p[0 + m];
        TA[0] = tv[12]; TA[1] = tv[13];
        group8r<false>(Bb, Cb, acc, TB);
        Mb -= 27;
        Mb -= 27;
        tv += 12;
    }

    const int nb = n0 + 8 * t;
#pragma unroll
    for (int j = 0; j < 8; j++)
        if (nb + j < NSAMP) y[nb + j] = acc[j];
}

#define ESLICE 2880

__global__ __launch_bounds__(BLOCK)
void env_fwd(const float* __restrict__ in, const float* __restrict__ taps,
             float* __restrict__ out)
{
    extern __shared__ float Sh[];
    const int wid  = threadIdx.x >> 6;
    const int lane = threadIdx.x & 63;
    float* s = Sh + wid * ESLICE;
    const int gw  = blockIdx.x * 4 + wid;
    const int c   = gw / NT512;
    const int n0w = (gw % NT512) * WTILE;
    constexpr int Lpad = LP_ENV;
    const float* __restrict__ xin = in + (long)c * NSAMP;

    constexpr int E = WTILE + Lpad - 1;
    for (int i = lane; i < E; i += 64) {
        int p = n0w - (Lpad - 1) + i;
        s[phys9(i + 9)] = (p >= 0 && p < NSAMP) ? fabsf(xin[p]) : 0.f;
    }
    __syncthreads();

    constexpr int LB = Lpad / 8;
    const int B = 9 * (lane + LB);
    const f32x4* tv = (const f32x4*)(taps + (long)c * Lpad);

    float Ab[8], Bb[8], Cb[8];
    float acc[8] = {0,0,0,0,0,0,0,0};
#pragma unroll
    for (int m = 0; m < 8; m++) Ab[m] = s[B + m];
#pragma unroll
    for (int m = 0; m < 8; m++) Bb[m] = s[B + 9 + m];
    f32x4 TA[2], TB[2];
    TA[0] = tv[0]; TA[1] = tv[1];

    int Mb = B - 54;
    constexpr int NIT6 = Lpad / 48;
#pragma unroll 1
    for (int im = 0; im < NIT6; ++im) {
        const float* p = s + Mb;
#pragma unroll
        for (int m = 0; m < 8; m++) Cb[m] = p[45 + m];
        TB[0] = tv[2];  TB[1] = tv[3];
        group8r<false>(Ab, Bb, acc, TA);
#pragma unroll
        for (int m = 0; m < 8; m++) Bb[m] = p[36 + m];
        TA[0] = tv[4];  TA[1] = tv[5];
        group8r<false>(Cb, Ab, acc, TB);
#pragma unroll
        for (int m = 0; m < 8; m++) Ab[m] = p[27 + m];
        TB[0] = tv[6];  TB[1] = tv[7];
        group8r<false>(Bb, Cb, acc, TA);
#pragma unroll
        for (int m = 0; m < 8; m++) Cb[m] = p[18 + m];
        TA[0] = tv[8];  TA[1] = tv[9];
        group8r<false>(Ab, Bb, acc, TB);
#pragma unroll
        for (int m = 0; m < 8; m++) Bb[m] = p[9 + m];
        TB[0] = tv[10]; TB[1] = tv[11];
        group8r<false>(Cb, Ab, acc, TA);
#pragma unroll
        for (int m = 0; m < 8; m++) Ab[m] = p[0 + m];
        TA[0] = tv[12]; TA[1] = tv[13];
        group8r<false>(Bb, Cb, acc, TB);
        Mb -= 54;
        tv += 12;
    }

    float* y = out + (long)c * NSAMP;
    const int nb = n0w + 8 * lane;
#pragma unroll
    for (int j = 0; j < 8; j++)
        if (nb + j < NSAMP) y[nb + j] = acc[j];
}

__global__ __launch_bounds__(BLOCK)
void env_bwd_gain(const float* __restrict__ envf, const float* __restrict__ taps,
                  float* __restrict__ pc,
                  const float* __restrict__ ratios, const float* __restrict__ eqloud)
{
    extern __shared__ float Sh[];
    const int wid  = threadIdx.x >> 6;
    const int lane = threadIdx.x & 63;
    float* s = Sh + wid * ESLICE;
    const int gw  = blockIdx.x * 4 + wid;
    const int c   = gw / NT512;
    const int n0w = (gw % NT512) * WTILE;
    constexpr int Lpad = LP_ENV;
    const float* __restrict__ xin = envf + (long)c * NSAMP;

    constexpr int E2 = WTILE + Lpad + 8;
    for (int i = lane; i < E2; i += 64) {
        int p = n0w + i;
        s[phys9(i)] = (p < NSAMP) ? fabsf(xin[p]) : 0.f;
    }
    __syncthreads();

    const f32x4* tv = (const f32x4*)(taps + (long)c * Lpad);
    float Ab[8], Bb[8], Cb[8];
    float acc[8] = {0,0,0,0,0,0,0,0};
#pragma unroll
    for (int m = 0; m < 8; m++) Ab[m] = s[9 * lane + m];
#pragma unroll
    for (int m = 0; m < 8; m++) Bb[m] = s[9 * lane + 9 + m];
    f32x4 TA[2], TB[2];
    TA[0] = tv[0]; TA[1] = tv[1];

    int Mb = 9 * lane;
    constexpr int NIT6 = Lpad / 48;
#pragma unroll 1
    for (int im = 0; im < NIT6; ++im) {
        const float* p = s + Mb;
#pragma unroll
        for (int m = 0; m < 8; m++) Cb[m] = p[18 + m];
        TB[0] = tv[2];  TB[1] = tv[3];
        group8r<true>(Ab, Bb, acc, TA);
#pragma unroll
        for (int m = 0; m < 8; m++) Ab[m] = p[27 + m];
        TA[0] = tv[4];  TA[1] = tv[5];
        group8r<true>(Bb, Cb, acc, TB);
#pragma unroll
        for (int m = 0; m < 8; m++) Bb[m] = p[36 + m];
        TB[0] = tv[6];  TB[1] = tv[7];
        group8r<true>(Cb, Ab, acc, TA);
#pragma unroll
        for (int m = 0; m < 8; m++) Cb[m] = p[45 + m];
        TA[0] = tv[8];  TA[1] = tv[9];
        group8r<true>(Ab, Bb, acc, TB);
#pragma unroll
        for (int m = 0; m < 8; m++) Ab[m] = p[54 + m];
        TB[0] = tv[10]; TB[1] = tv[11];
        group8r<true>(Bb, Cb, acc, TA);
#pragma unroll
        for (int m = 0; m < 8; m++) Bb[m] = p[63 + m];
        TA[0] = tv[12]; TA[1] = tv[13];
        group8r<true>(Cb, Ab, acc, TB);
        Mb += 54;
        tv += 12;
    }

    const float emax = exp10f(0.05f * (eqloud[c] - 100.0f));
    const float er   = fmaxf(ratios[c], -5.0f) - 1.0f;
    const int nb = n0w + 8 * lane;
#pragma unroll
    for (int j = 0; j < 8; j++) {
        int n = nb + j;
        if (n < NSAMP) {
            float env = acc[j];
            float ecl = fminf(fmaxf(env, 1e-9f), emax);
            float enr = fmaxf(ecl / emax, 1e-6f);
            float g   = fminf(powf(enr, er), 100.0f);
            long id = (long)c * NSAMP + n;
            pc[id] = pc[id] * g;
        }
    }
}

__global__ void conv_self(const float* __restrict__ a, int astride, int La,
                          float* __restrict__ out, int ostride, int Mlen, int Mpad)
{
    extern __shared__ float s[];
    const int c = blockIdx.y;
    const float* __restrict__ ar = a + (long)c * astride;
    for (int i = threadIdx.x; i < La; i += blockDim.x) s[i] = ar[i];
    __syncthreads();
    int m = blockIdx.x * blockDim.x + threadIdx.x;
    float acc = 0.f;
    for (int k = 0; k < La; k++) {
        int mi = m - k;
        float bv = ((unsigned)mi < (unsigned)La) ? s[mi] : 0.f;
        acc = fmaf(s[k], bv, acc);
    }
    if (m < Mpad) out[(long)c * ostride + m] = (m < Mlen) ? acc : 0.f;
}

__global__ void pad_copy(const float* __restrict__ src, int L, int sstride,
                         float* __restrict__ dst, int Lpad)
{
    int c = blockIdx.y;
    int k = blockIdx.x * blockDim.x + threadIdx.x;
    if (k < Lpad) dst[(long)c * Lpad + k] = (k < L) ? src[(long)c * sstride + k] : 0.f;
}

__global__ void delay_copy(const float* __restrict__ a, float* __restrict__ b,
                           const int* __restrict__ delays)
{
    int c = blockIdx.y;
    int n = blockIdx.x * blockDim.x + threadIdx.x;
    if (n < NSAMP) {
        int q = n + delays[c];
        b[(long)c * NSAMP + n] = (q < NSAMP) ? a[(long)c * NSAMP + q] : 0.f;
    }
}

__global__ void reduce_coch(const float* __restrict__ b, float* __restrict__ coch)
{
    int n = blockIdx.x * blockDim.x + threadIdx.x;
    if (n < NSAMP) {
        float sum = 0.f;
        for (int c = 0; c < NCH; c++) sum += b[(long)c * NSAMP + n];
        coch[n] = sum * 0.31622776601683794f;
    }
}

static inline size_t lds_blk(int Lpad)
{
    int umax = TILE + Lpad + 8;
    return (size_t)(umax + (umax >> 3) + 16) * 4;
}

extern "C" void kernel_launch(void* const* d_in, const int* in_sizes, int n_in,
                              void* d_out, int out_size, void* d_ws, size_t ws_size,
                              hipStream_t stream)
{
    const float* x       = (const float*)d_in[0];
    const float* src_fwd = (const float*)d_in[1];
    const float* src_bwd = (const float*)d_in[2];
    const float* lpf     = (const float*)d_in[3];
    const float* gtn     = (const float*)d_in[4];  // [28,1000]
    const float* hp      = (const float*)d_in[5];  // [24,1000]
    const float* clpf    = (const float*)d_in[6];  // [28,2000]
    const float* ratios  = (const float*)d_in[7];
    const float* eqloud  = (const float*)d_in[8];
    const int*   delays  = (const int*)d_in[9];
    float* out = (float*)d_out;

    float* ws   = (float*)d_ws;
    const size_t CNs = (size_t)NCH * NSAMP;
    float* bufA  = ws;                           // C*N (y4, then env_f)
    float* bufB  = bufA + CNs;                   // C*N (pass_del -> coch_c)
    float* xc    = bufB + CNs;                   // N
    float* coch  = xc + NSAMP;                   // N
    float* t1    = coch + NSAMP;                 // N
    float* h2    = t1 + NSAMP;                   // 28*2000
    float* h4    = h2 + (size_t)NCH * 2000;      // 28*LP_GT4
    float* hpP   = h4 + (size_t)NCH * LP_GT4;    // 24*LP_HP
    float* clpfP = hpP + (size_t)HPCH * LP_HP;   // 28*LP_ENV
    float* sfP   = clpfP + (size_t)NCH * LP_ENV; // LP_SRC
    float* sbP   = sfP + LP_SRC;                 // LP_SRC
    float* lpP   = sbP + LP_SRC;                 // LP_LPF
    // fragment-ordered bf16 taps (16B aligned: offset from ws is multiple of 4 floats)
    unsigned short* TF = (unsigned short*)(lpP + LP_LPF);  // 258048 ushorts

    dim3 blk(BLOCK);
    const int NT = (NSAMP + TILE - 1) / TILE;    // 108
    const int EGRID = (NT512 * NCH) / 4;         // 3017

    // --- filter prep ---
    conv_self<<<dim3(8, NCH), blk, L_GT * 4, stream>>>(
        gtn, L_GT, L_GT, h2, 2000, 1999, 1999);
    conv_self<<<dim3((LP_GT4 + BLOCK - 1) / BLOCK, NCH), blk, 1999 * 4, stream>>>(
        h2, 2000, 1999, h4, LP_GT4, 3997, LP_GT4);
    frag_taps<<<dim3(KSTEPS), blk, 0, stream>>>(h4, TF);
    pad_copy<<<dim3(4, HPCH), blk, 0, stream>>>(hp, L_GT, L_GT, hpP, LP_HP);
    pad_copy<<<dim3(8, NCH), blk, 0, stream>>>(clpf, L_ENV, L_ENV, clpfP, LP_ENV);
    pad_copy<<<dim3(2, 1), blk, 0, stream>>>(src_fwd, 256, 256, sfP, LP_SRC);
    pad_copy<<<dim3(2, 1), blk, 0, stream>>>(src_bwd, 256, 256, sbP, LP_SRC);
    pad_copy<<<dim3(1, 1), blk, 0, stream>>>(lpf, 133, 133, lpP, LP_LPF);

    // --- signal path ---
    fir_blk<LP_SRC, false><<<dim3(NT, 1), blk, lds_blk(LP_SRC), stream>>>(
        x, 0, sfP, LP_SRC, xc, 0, nullptr, 0);

    // y4 = gammatone^4 via MFMA Toeplitz GEMM
    gt4_mfma<<<dim3(GTGRID), blk, 2 * VPITCH * 4, stream>>>(xc, TF, bufA);

    delay_copy<<<dim3((NSAMP + BLOCK - 1) / BLOCK, 4), blk, 0, stream>>>(bufA, bufB, delays);

    fir_blk<LP_HP, true><<<dim3(NT, HPCH), blk, lds_blk(LP_HP), stream>>>(
        bufA + 4 * (size_t)NSAMP, NSAMP, hpP, LP_HP,
        bufB + 4 * (size_t)NSAMP, NSAMP, delays, 4);

    env_fwd<<<dim3(EGRID), blk, 4 * ESLICE * 4, stream>>>(bufB, clpfP, bufA);

    env_bwd_gain<<<dim3(EGRID), blk, 4 * ESLICE * 4, stream>>>(
        bufA, clpfP, bufB, ratios, eqloud);

    reduce_coch<<<dim3((NSAMP + BLOCK - 1) / BLOCK), blk, 0, stream>>>(bufB, coch);

    fir_blk<LP_SRC, false><<<dim3(NT, 1), blk, lds_blk(LP_SRC), stream>>>(
        coch, 0, sbP, LP_SRC, t1, 0, nullptr, 0);
    fir_blk<LP_LPF, false><<<dim3(NT, 1), blk, lds_blk(LP_LPF), stream>>>(
        t1, 0, lpP, LP_LPF, out, 0, nullptr, 0);
}

// Round 7
// 500.855 us; speedup vs baseline: 3.0677x; 2.3445x over previous
//
#include <hip/hip_runtime.h>
#include <math.h>

// Problem constants
#define NSAMP 220500
#define NCH   28
#define HPCH  24
#define TILE  2048
#define BLOCK 256

// Padded tap lengths
#define LP_GT4 4032   // 3997 actual
#define LP_HP  1008   // 1000 actual
#define LP_ENV 2016   // 2000 actual
#define LP_SRC 288    // 256 actual
#define LP_LPF 144    // 133 actual

// K-step counts for the MFMA Toeplitz FIRs (derived: desc NC = ceil(L/32)+1,
// asc NC = ceil((L-1+15)/32)+1 with true L; all verified cover k in [0,L))
#define NC_GT 126
#define NC_HP 33
#define NC_EF 64
#define NC_EB 63

typedef __attribute__((ext_vector_type(4))) float f32x4;
typedef __attribute__((ext_vector_type(8))) short bf16x8;

// Odd-stride LDS swizzle on dword index (proven round 4: odd lane strides <=2-way)
__device__ __forceinline__ int phys9(int u) { return u + (u >> 3); }

__device__ __forceinline__ unsigned short f2bf(float x) {
    unsigned u = __float_as_uint(x);
    u += 0x7FFFu + ((u >> 16) & 1u);
    return (unsigned short)(u >> 16);
}

#define MFMA32 __builtin_amdgcn_mfma_f32_16x16x32_bf16

// ===========================================================================
// A-fragment prep: Toeplitz taps, fragment-ordered.
//   desc: A_s[m][kap] = h[32s + m - 1 - kap]
//   asc:  A_s[m][kap] = h[32s + kap - m]
// Fragment layout (proven in round-6 gt4): elem i of lane l = A[l&15][8*(l>>4)+i].
// ===========================================================================
__global__ void prep_frag(const float* __restrict__ taps, int pitch,
                          unsigned short* __restrict__ TF, int NC,
                          int isAsc, int split, long planeStride)
{
    const int s  = blockIdx.x;
    const int ch = blockIdx.y;
    const int l  = threadIdx.x;           // 64 threads
    const int m  = l & 15, hib = (l >> 4) * 8;
    unsigned short* dst = TF + ((size_t)ch * NC + s) * 512 + l * 8;
#pragma unroll
    for (int i = 0; i < 8; i++) {
        int kap = hib + i;
        int k = isAsc ? (32 * s + kap - m) : (32 * s + m - 1 - kap);
        float val = (k >= 0 && k < pitch) ? taps[(size_t)ch * pitch + k] : 0.f;
        unsigned short hh = f2bf(val);
        dst[i] = hh;
        if (split) {
            float fh = __uint_as_float((unsigned)hh << 16);
            dst[planeStride + i] = f2bf(val - fh);
        }
    }
}

// ===========================================================================
// Unified per-channel Toeplitz MFMA FIR.
// Block = (channel, 4096 outputs); 4 waves x 4 j-tiles x 256 outputs.
// B staged in LDS as bf16, dword-phys9-swizzled; all B reads even-aligned
// (16-elem n-stride), 4x b32 per fragment, <=2-way banks.
//   desc: B idx = jb + 16n + kap + 1 - 32c ; asc: B idx = jb + 16n + 32c + kap
// D layout: col n = lane&15, row m = 4*(lane>>4)+r -> j = jb+1024w+256jt+16n+4hi+r
// GAIN: fused recruitment epilogue, out = pass_del (in-place multiply).
// ===========================================================================
template<int NC, bool ASC, bool SPLIT, bool ABSIN, bool DELAYED, bool GAIN>
__global__ __launch_bounds__(BLOCK)
void fir_mfma_pc(const float* __restrict__ in, long instride,
                 const unsigned short* __restrict__ TF, long planeStride,
                 float* __restrict__ out,
                 const int* __restrict__ delays, int chan0,
                 const float* __restrict__ ratios,
                 const float* __restrict__ eqloud)
{
    extern __shared__ float S[];
    unsigned short* sw = (unsigned short*)S;
    const int c  = blockIdx.y;
    const int jb = blockIdx.x * 4096;
    const float* __restrict__ xin = in + (long)c * instride;
    constexpr int E = 4112 + 32 * (NC - 1);
    const int o = ASC ? jb : (jb + 1 - 32 * (NC - 1));
    int d = 0;
    if (DELAYED) d = delays[chan0 + c];

    for (int e = threadIdx.x; e < E; e += BLOCK) {
        int p = o + e;
        float v = 0.f;
        if (DELAYED) { if (p >= 0 && p + d < NSAMP) v = xin[p + d]; }
        else         { if (p >= 0 && p < NSAMP)     v = xin[p]; }
        if (ABSIN) v = fabsf(v);
        sw[2 * phys9(e >> 1) + (e & 1)] = f2bf(v);
    }
    __syncthreads();

    const int lane = threadIdx.x & 63;
    const int w    = threadIdx.x >> 6;
    const int n    = lane & 15;
    const int hi   = lane >> 4;
    // v0 mod 8 = 4*hi in {0,4}: 4 consecutive dword reads stay in one 8-block
    int vp = phys9(8 * n + 4 * hi + 512 * w + (ASC ? 0 : 16 * (NC - 1)));
    constexpr int DSTEP = ASC ? 18 : -18;   // +-16 dwords -> +-18 phys

    const unsigned short* tp = TF + (size_t)c * NC * 512 + lane * 8;

    f32x4 ac0 = {0,0,0,0}, ac1 = {0,0,0,0}, ac2 = {0,0,0,0}, ac3 = {0,0,0,0};
    bf16x8 Ah = *(const bf16x8*)tp;
    bf16x8 Al = Ah;
    if (SPLIT) Al = *(const bf16x8*)(tp + planeStride);

#pragma unroll 1
    for (int s = 0; s < NC; ++s) {
        bf16x8 Nh = Ah, Nl = Al;
        if (s + 1 < NC) {
            Nh = *(const bf16x8*)(tp + (size_t)(s + 1) * 512);
            if (SPLIT) Nl = *(const bf16x8*)(tp + planeStride + (size_t)(s + 1) * 512);
        }
        const float* sp = S + vp;
        union U { float f[4]; bf16x8 v; };
        U b0, b1, b2, b3;
        b0.f[0]=sp[0];   b0.f[1]=sp[1];   b0.f[2]=sp[2];   b0.f[3]=sp[3];
        b1.f[0]=sp[144]; b1.f[1]=sp[145]; b1.f[2]=sp[146]; b1.f[3]=sp[147];
        b2.f[0]=sp[288]; b2.f[1]=sp[289]; b2.f[2]=sp[290]; b2.f[3]=sp[291];
        b3.f[0]=sp[432]; b3.f[1]=sp[433]; b3.f[2]=sp[434]; b3.f[3]=sp[435];
        ac0 = MFMA32(Ah, b0.v, ac0, 0, 0, 0);
        ac1 = MFMA32(Ah, b1.v, ac1, 0, 0, 0);
        ac2 = MFMA32(Ah, b2.v, ac2, 0, 0, 0);
        ac3 = MFMA32(Ah, b3.v, ac3, 0, 0, 0);
        if (SPLIT) {
            ac0 = MFMA32(Al, b0.v, ac0, 0, 0, 0);
            ac1 = MFMA32(Al, b1.v, ac1, 0, 0, 0);
            ac2 = MFMA32(Al, b2.v, ac2, 0, 0, 0);
            ac3 = MFMA32(Al, b3.v, ac3, 0, 0, 0);
        }
        Ah = Nh;
        if (SPLIT) Al = Nl;
        vp += DSTEP;
    }

    float* __restrict__ yo = out + (long)c * NSAMP;
    const int j0 = jb + 1024 * w + 16 * n + 4 * hi;   // multiple of 4; NSAMP%4==0

    if (!GAIN) {
        if (j0 < NSAMP)       *(f32x4*)(yo + j0)       = ac0;
        if (j0 + 256 < NSAMP) *(f32x4*)(yo + j0 + 256) = ac1;
        if (j0 + 512 < NSAMP) *(f32x4*)(yo + j0 + 512) = ac2;
        if (j0 + 768 < NSAMP) *(f32x4*)(yo + j0 + 768) = ac3;
    } else {
        const float emax = exp10f(0.05f * (eqloud[c] - 100.0f));
        const float er   = fmaxf(ratios[c], -5.0f) - 1.0f;
#define GAINST(ACC, OFS) { int j = j0 + (OFS); if (j < NSAMP) {            \
            f32x4 pv = *(f32x4*)(yo + j);                                   \
            _Pragma("unroll")                                               \
            for (int r = 0; r < 4; r++) {                                   \
                float env = ACC[r];                                         \
                float ecl = fminf(fmaxf(env, 1e-9f), emax);                 \
                float enr = fmaxf(ecl / emax, 1e-6f);                       \
                float g   = fminf(powf(enr, er), 100.0f);                   \
                pv[r] *= g;                                                 \
            }                                                               \
            *(f32x4*)(yo + j) = pv; } }
        GAINST(ac0, 0) GAINST(ac1, 256) GAINST(ac2, 512) GAINST(ac3, 768)
#undef GAINST
    }
}

// host-side LDS bytes for the MFMA FIR
static inline size_t lds_pc(int NC)
{
    int E = 4112 + 32 * (NC - 1);
    int D = (E + 1) / 2;
    return (size_t)(D + (D >> 3) + 8) * 4;
}

// ===========================================================================
// VALU FIR (proven rounds 4-6) for the three tiny chain FIRs
// ===========================================================================
template<bool ASC>
__device__ __forceinline__ void group8r(const float (&LO)[8], const float (&HI)[8],
                                        float (&acc)[8], const f32x4 (&T)[2])
{
#pragma unroll
    for (int kp = 0; kp < 8; kp++) {
        const float hk = T[kp >> 2][kp & 3];
#pragma unroll
        for (int j = 0; j < 8; j++) {
            const int m = ASC ? (j + kp) : (8 + j - kp);
            const float w = (m < 8) ? LO[m] : HI[m - 8];
            acc[j] = fmaf(hk, w, acc[j]);
        }
    }
}

template<int Lpad, bool DELAYED>
__global__ __launch_bounds__(BLOCK)
void fir_blk(const float* __restrict__ in, long instride,
             const float* __restrict__ taps, int tapstride,
             float* __restrict__ out, long ostride,
             const int* __restrict__ delays, int chan0)
{
    extern __shared__ float s[];
    const int c  = blockIdx.y;
    const int n0 = blockIdx.x * TILE;
    const float* __restrict__ xin = in + (long)c * instride;
    float* __restrict__ y         = out + (long)c * ostride;
    int d = 0;
    if (DELAYED) d = delays[chan0 + c];

    constexpr int E = TILE + Lpad - 1;
    for (int i = threadIdx.x; i < E; i += BLOCK) {
        int p = n0 - (Lpad - 1) + i;
        float v = 0.f;
        if (p >= 0 && p < NSAMP) {
            int q = p + d;
            if (!DELAYED || q < NSAMP) v = xin[q];
        }
        s[phys9(i + 9)] = v;
    }
    __syncthreads();

    const int t = threadIdx.x;
    constexpr int LB = Lpad / 8;
    const int B = 9 * (t + LB);
    const f32x4* tv = (const f32x4*)(taps + (long)c * tapstride);

    float Ab[8], Bb[8], Cb[8];
    float acc[8] = {0,0,0,0,0,0,0,0};
#pragma unroll
    for (int m = 0; m < 8; m++) Ab[m] = s[B + m];
#pragma unroll
    for (int m = 0; m < 8; m++) Bb[m] = s[B + 9 + m];
    f32x4 TA[2], TB[2];
    TA[0] = tv[0]; TA[1] = tv[1];

    int Mb = B - 54;
    constexpr int NIT6 = Lpad / 48;
#pragma unroll 1
    for (int im = 0; im < NIT6; ++im) {
        const float* p = s + Mb;
#pragma unroll
        for (int m = 0; m < 8; m++) Cb[m] = p[45 + m];
        TB[0] = tv[2];  TB[1] = tv[3];
        group8r<false>(Ab, Bb, acc, TA);
#pragma unroll
        for (int m = 0; m < 8; m++) Bb[m] = p[36 + m];
        TA[0] = tv[4];  TA[1] = tv[5];
        group8r<false>(Cb, Ab, acc, TB);
#pragma unroll
        for (int m = 0; m < 8; m++) Ab[m] = p[27 + m];
        TB[0] = tv[6];  TB[1] = tv[7];
        group8r<false>(Bb, Cb, acc, TA);
#pragma unroll
        for (int m = 0; m < 8; m++) Cb[m] = p[18 + m];
        TA[0] = tv[8];  TA[1] = tv[9];
        group8r<false>(Ab, Bb, acc, TB);
#pragma unroll
        for (int m = 0; m < 8; m++) Bb[m] = p[9 + m];
        TB[0] = tv[10]; TB[1] = tv[11];
        group8r<false>(Cb, Ab, acc, TA);
#pragma unroll
        for (int m = 0; m < 8; m++) Ab[m] = p[0 + m];
        TA[0] = tv[12]; TA[1] = tv[13];
        group8r<false>(Bb, Cb, acc, TB);
        Mb -= 54;
        tv += 12;
    }

    const int nb = n0 + 8 * t;
#pragma unroll
    for (int j = 0; j < 8; j++)
        if (nb + j < NSAMP) y[nb + j] = acc[j];
}

static inline size_t lds_blk(int Lpad)
{
    int umax = TILE + Lpad + 8;
    return (size_t)(umax + (umax >> 3) + 16) * 4;
}

// ===========================================================================
// Small helpers
// ===========================================================================
__global__ void conv_self(const float* __restrict__ a, int astride, int La,
                          float* __restrict__ out, int ostride, int Mlen, int Mpad)
{
    extern __shared__ float s[];
    const int c = blockIdx.y;
    const float* __restrict__ ar = a + (long)c * astride;
    for (int i = threadIdx.x; i < La; i += blockDim.x) s[i] = ar[i];
    __syncthreads();
    int m = blockIdx.x * blockDim.x + threadIdx.x;
    float acc = 0.f;
    for (int k = 0; k < La; k++) {
        int mi = m - k;
        float bv = ((unsigned)mi < (unsigned)La) ? s[mi] : 0.f;
        acc = fmaf(s[k], bv, acc);
    }
    if (m < Mpad) out[(long)c * ostride + m] = (m < Mlen) ? acc : 0.f;
}

__global__ void pad_copy(const float* __restrict__ src, int L, int sstride,
                         float* __restrict__ dst, int Lpad)
{
    int c = blockIdx.y;
    int k = blockIdx.x * blockDim.x + threadIdx.x;
    if (k < Lpad) dst[(long)c * Lpad + k] = (k < L) ? src[(long)c * sstride + k] : 0.f;
}

__global__ void delay_copy(const float* __restrict__ a, float* __restrict__ b,
                           const int* __restrict__ delays)
{
    int c = blockIdx.y;
    int n = blockIdx.x * blockDim.x + threadIdx.x;
    if (n < NSAMP) {
        int q = n + delays[c];
        b[(long)c * NSAMP + n] = (q < NSAMP) ? a[(long)c * NSAMP + q] : 0.f;
    }
}

__global__ void reduce_coch(const float* __restrict__ b, float* __restrict__ coch)
{
    int n = blockIdx.x * blockDim.x + threadIdx.x;
    if (n < NSAMP) {
        float sum = 0.f;
        for (int c = 0; c < NCH; c++) sum += b[(long)c * NSAMP + n];
        coch[n] = sum * 0.31622776601683794f;
    }
}

extern "C" void kernel_launch(void* const* d_in, const int* in_sizes, int n_in,
                              void* d_out, int out_size, void* d_ws, size_t ws_size,
                              hipStream_t stream)
{
    const float* x       = (const float*)d_in[0];
    const float* src_fwd = (const float*)d_in[1];
    const float* src_bwd = (const float*)d_in[2];
    const float* lpf     = (const float*)d_in[3];
    const float* gtn     = (const float*)d_in[4];  // [28,1000]
    const float* hp      = (const float*)d_in[5];  // [24,1000]
    const float* clpf    = (const float*)d_in[6];  // [28,2000]
    const float* ratios  = (const float*)d_in[7];
    const float* eqloud  = (const float*)d_in[8];
    const int*   delays  = (const int*)d_in[9];
    float* out = (float*)d_out;

    float* ws   = (float*)d_ws;
    const size_t CNs = (size_t)NCH * NSAMP;
    float* bufA  = ws;                           // C*N (y4, then env_f)
    float* bufB  = bufA + CNs;                   // C*N (pass_del -> coch_c)
    float* xc    = bufB + CNs;                   // N
    float* coch  = xc + NSAMP;                   // N
    float* t1    = coch + NSAMP;                 // N
    float* h2    = t1 + NSAMP;                   // 28*2000
    float* h4    = h2 + (size_t)NCH * 2000;      // 28*LP_GT4
    float* hpP   = h4 + (size_t)NCH * LP_GT4;    // 24*LP_HP
    float* clpfP = hpP + (size_t)HPCH * LP_HP;   // 28*LP_ENV
    float* sfP   = clpfP + (size_t)NCH * LP_ENV; // LP_SRC
    float* sbP   = sfP + LP_SRC;                 // LP_SRC
    float* lpP   = sbP + LP_SRC;                 // LP_LPF

    // fragment-ordered bf16 Toeplitz taps (16B-aligned: all prior sizes %4==0)
    unsigned short* TFgt = (unsigned short*)(lpP + LP_LPF);
    const long gtPlane = (long)NCH * NC_GT * 512;            // 1,806,336 ushorts
    unsigned short* TFhp = TFgt + 2 * gtPlane;
    unsigned short* TFef = TFhp + (size_t)HPCH * NC_HP * 512;
    unsigned short* TFeb = TFef + (size_t)NCH * NC_EF * 512;

    dim3 blk(BLOCK);
    const int NT  = (NSAMP + TILE - 1) / TILE;   // 108
    const int NB4 = (NSAMP + 4095) / 4096;       // 54

    // --- filter prep ---
    conv_self<<<dim3(8, NCH), blk, 1000 * 4, stream>>>(
        gtn, 1000, 1000, h2, 2000, 1999, 1999);
    conv_self<<<dim3((LP_GT4 + BLOCK - 1) / BLOCK, NCH), blk, 1999 * 4, stream>>>(
        h2, 2000, 1999, h4, LP_GT4, 3997, LP_GT4);
    pad_copy<<<dim3(4, HPCH), blk, 0, stream>>>(hp, 1000, 1000, hpP, LP_HP);
    pad_copy<<<dim3(8, NCH), blk, 0, stream>>>(clpf, 2000, 2000, clpfP, LP_ENV);
    pad_copy<<<dim3(2, 1), blk, 0, stream>>>(src_fwd, 256, 256, sfP, LP_SRC);
    pad_copy<<<dim3(2, 1), blk, 0, stream>>>(src_bwd, 256, 256, sbP, LP_SRC);
    pad_copy<<<dim3(1, 1), blk, 0, stream>>>(lpf, 133, 133, lpP, LP_LPF);

    prep_frag<<<dim3(NC_GT, NCH), dim3(64), 0, stream>>>(
        h4, LP_GT4, TFgt, NC_GT, 0, 1, gtPlane);
    prep_frag<<<dim3(NC_HP, HPCH), dim3(64), 0, stream>>>(
        hpP, LP_HP, TFhp, NC_HP, 0, 0, 0);
    prep_frag<<<dim3(NC_EF, NCH), dim3(64), 0, stream>>>(
        clpfP, LP_ENV, TFef, NC_EF, 0, 0, 0);
    prep_frag<<<dim3(NC_EB, NCH), dim3(64), 0, stream>>>(
        clpfP, LP_ENV, TFeb, NC_EB, 1, 0, 0);

    // --- signal path ---
    // xc = fir1(x, src_fwd)
    fir_blk<LP_SRC, false><<<dim3(NT, 1), blk, lds_blk(LP_SRC), stream>>>(
        x, 0, sfP, LP_SRC, xc, 0, nullptr, 0);

    // y4 = gammatone^4 (collapsed), per-channel MFMA, split taps
    fir_mfma_pc<NC_GT, false, true, false, false, false>
        <<<dim3(NB4, NCH), blk, lds_pc(NC_GT), stream>>>(
        xc, 0, TFgt, gtPlane, bufA, nullptr, 0, nullptr, nullptr);

    // pass_del ch 0..3: delayed copy
    delay_copy<<<dim3((NSAMP + BLOCK - 1) / BLOCK, 4), blk, 0, stream>>>(
        bufA, bufB, delays);

    // pass_del ch 4..27: HP with delay fetched at staging
    fir_mfma_pc<NC_HP, false, false, false, true, false>
        <<<dim3(NB4, HPCH), blk, lds_pc(NC_HP), stream>>>(
        bufA + 4 * (size_t)NSAMP, NSAMP, TFhp, 0, bufB + 4 * (size_t)NSAMP,
        delays, 4, nullptr, nullptr);

    // env_f = causal fir(|pass_del|, clpf)
    fir_mfma_pc<NC_EF, false, false, true, false, false>
        <<<dim3(NB4, NCH), blk, lds_pc(NC_EF), stream>>>(
        bufB, NSAMP, TFef, 0, bufA, nullptr, 0, nullptr, nullptr);

    // env = anti-causal fir(|env_f|, clpf) + fused recruitment gain into pass_del
    fir_mfma_pc<NC_EB, true, false, true, false, true>
        <<<dim3(NB4, NCH), blk, lds_pc(NC_EB), stream>>>(
        bufA, NSAMP, TFeb, 0, bufB, nullptr, 0, ratios, eqloud);

    // coch = 10^-0.5 * sum_c coch_c
    reduce_coch<<<dim3((NSAMP + BLOCK - 1) / BLOCK), blk, 0, stream>>>(bufB, coch);

    // out = fir1(fir1(coch, src_bwd), lpf)
    fir_blk<LP_SRC, false><<<dim3(NT, 1), blk, lds_blk(LP_SRC), stream>>>(
        coch, 0, sbP, LP_SRC, t1, 0, nullptr, 0);
    fir_blk<LP_LPF, false><<<dim3(NT, 1), blk, lds_blk(LP_LPF), stream>>>(
        t1, 0, lpP, LP_LPF, out, 0, nullptr, 0);
}

// Round 8
// 496.547 us; speedup vs baseline: 3.0943x; 1.0087x over previous
//
#include <hip/hip_runtime.h>
#include <math.h>

// Problem constants
#define NSAMP 220500
#define NCH   28
#define HPCH  24
#define TILE  2048
#define BLOCK 256

// Tap geometry
#define LP_GT4 4032   // h4 stride (3997 actual)
#define L_H4F  4252   // src_fwd (*) h4 combined length
#define LP_H4F 4288   // h4f stride = 134*32
#define LP_HP  1008   // 1000 actual
#define LP_ENV 2016   // 2000 actual
#define L_TB   388    // lpf (*) src_bwd
#define LP_TB  432    // padded for fir_blk (48*9)

// K-step counts
#define NC_GT 134     // 16x16x32 desc: 32(NC-1) >= L+... covers k in [0,4252)
#define NC_HP 65      // 32x32x16 desc: 16(NC-1)-17 >= 999
#define NC_EF 128     // 32x32x16 desc: 16(NC-1)-17 >= 2015
#define NC_EB 128     // 32x32x16 asc:  16(NC-1)+15 >= 2015+31

typedef __attribute__((ext_vector_type(4)))  float f32x4;
typedef __attribute__((ext_vector_type(16))) float f32x16;
typedef __attribute__((ext_vector_type(8)))  short bf16x8;

// fir_blk swizzle (proven round 4)
__device__ __forceinline__ int phys9(int u) { return u + (u >> 3); }

__device__ __forceinline__ unsigned short f2bf(float x) {
    unsigned u = __float_as_uint(x);
    u += 0x7FFFu + ((u >> 16) & 1u);
    return (unsigned short)(u >> 16);
}

#define MFMA16 __builtin_amdgcn_mfma_f32_16x16x32_bf16
#define MFMA32 __builtin_amdgcn_mfma_f32_32x32x16_bf16

// ===========================================================================
// Tap prep, 16x16x32 (gt4): A_s[m][kap] = h[32s + m - 1 - kap], frag order
// elem i of lane l = A[l&15][8*(l>>4)+i]; hi+lo split planes.
// ===========================================================================
__global__ void prep_frag(const float* __restrict__ taps, int pitch,
                          unsigned short* __restrict__ TF, int NC,
                          int isAsc, int split, long planeStride)
{
    const int s  = blockIdx.x;
    const int ch = blockIdx.y;
    const int l  = threadIdx.x;           // 64 threads
    const int m  = l & 15, hib = (l >> 4) * 8;
    unsigned short* dst = TF + ((size_t)ch * NC + s) * 512 + l * 8;
#pragma unroll
    for (int i = 0; i < 8; i++) {
        int kap = hib + i;
        int k = isAsc ? (32 * s + kap - m) : (32 * s + m - 1 - kap);
        float val = (k >= 0 && k < pitch) ? taps[(size_t)ch * pitch + k] : 0.f;
        unsigned short hh = f2bf(val);
        dst[i] = hh;
        if (split) {
            float fh = __uint_as_float((unsigned)hh << 16);
            dst[planeStride + i] = f2bf(val - fh);
        }
    }
}

// ===========================================================================
// Tap prep, 32x32x16: elem i of lane l = A[l&31][8*(l>>5)+i].
//   desc: A_s[m][kap] = h[16s + m - 17 - kap]
//   asc : A_s[m][kap] = h[16s + kap - m]
// ===========================================================================
__global__ void prep_frag32(const float* __restrict__ taps, int pitch,
                            unsigned short* __restrict__ TF, int NC, int isAsc)
{
    const int s  = blockIdx.x;
    const int ch = blockIdx.y;
    const int l  = threadIdx.x;           // 64 threads
    const int m  = l & 31, kb = (l >> 5) * 8;
    unsigned short* dst = TF + ((size_t)ch * NC + s) * 512 + l * 8;
#pragma unroll
    for (int i = 0; i < 8; i++) {
        int kap = kb + i;
        int k = isAsc ? (16 * s + kap - m) : (16 * s + m - 17 - kap);
        float val = (k >= 0 && k < pitch) ? taps[(size_t)ch * pitch + k] : 0.f;
        dst[i] = f2bf(val);
    }
}

// ===========================================================================
// gt4: 4 channels/block share one staged x window (x is channel-shared).
// Block = 2048 outputs (4 waves x 2 j-tiles x 256), grid (108, 7).
// B_s[kap][n] = x[jb + 512w + 256jt + 16n + kap + 1 - 32s]; phys16 swizzle:
// v0 = 256w+128jt+8n+4hib+16(NC-1)-16s, vp = v0+(v0>>4), step -17, jt +136.
// ===========================================================================
__global__ __launch_bounds__(BLOCK)
void gt4_mfma4(const float* __restrict__ x, const unsigned short* __restrict__ TF,
               long plane, float* __restrict__ out)
{
    extern __shared__ float S[];
    unsigned* S32 = (unsigned*)S;
    const int jb = blockIdx.x * 2048;
    const int c0 = blockIdx.y * 4;
    const int o  = jb - 4255;             // jb + 1 - 32*(NC_GT-1)
    const int DW = 3160;                  // (2064 + 4255 + 1)/2

    for (int v = threadIdx.x; v < DW; v += BLOCK) {
        int p0 = o + 2 * v, p1 = p0 + 1;
        float a = (p0 >= 0 && p0 < NSAMP) ? x[p0] : 0.f;
        float b = (p1 >= 0 && p1 < NSAMP) ? x[p1] : 0.f;
        S32[v + (v >> 4)] = (unsigned)f2bf(a) | ((unsigned)f2bf(b) << 16);
    }
    __syncthreads();

    const int lane = threadIdx.x & 63;
    const int w    = threadIdx.x >> 6;
    const int n    = lane & 15;
    const int hib  = lane >> 4;
    int v0 = 256 * w + 8 * n + 4 * hib + 16 * (NC_GT - 1);
    int vp = v0 + (v0 >> 4);

    const unsigned short* t0  = TF + lane * 8;
    const unsigned short* tc0 = t0 + (size_t)(c0 + 0) * NC_GT * 512;
    const unsigned short* tc1 = t0 + (size_t)(c0 + 1) * NC_GT * 512;
    const unsigned short* tc2 = t0 + (size_t)(c0 + 2) * NC_GT * 512;
    const unsigned short* tc3 = t0 + (size_t)(c0 + 3) * NC_GT * 512;

    f32x4 a00={0,0,0,0}, a01={0,0,0,0}, a10={0,0,0,0}, a11={0,0,0,0};
    f32x4 a20={0,0,0,0}, a21={0,0,0,0}, a30={0,0,0,0}, a31={0,0,0,0};

    bf16x8 h0 = *(const bf16x8*)tc0, h1 = *(const bf16x8*)tc1;
    bf16x8 h2 = *(const bf16x8*)tc2, h3 = *(const bf16x8*)tc3;
    bf16x8 l0 = *(const bf16x8*)(tc0 + plane), l1 = *(const bf16x8*)(tc1 + plane);
    bf16x8 l2 = *(const bf16x8*)(tc2 + plane), l3 = *(const bf16x8*)(tc3 + plane);

#pragma unroll 1
    for (int s = 0; s < NC_GT; ++s) {
        int sn = (s + 1 < NC_GT) ? s + 1 : s;
        size_t off = (size_t)sn * 512;
        bf16x8 nh0 = *(const bf16x8*)(tc0 + off);
        bf16x8 nh1 = *(const bf16x8*)(tc1 + off);
        bf16x8 nh2 = *(const bf16x8*)(tc2 + off);
        bf16x8 nh3 = *(const bf16x8*)(tc3 + off);
        bf16x8 nl0 = *(const bf16x8*)(tc0 + plane + off);
        bf16x8 nl1 = *(const bf16x8*)(tc1 + plane + off);
        bf16x8 nl2 = *(const bf16x8*)(tc2 + plane + off);
        bf16x8 nl3 = *(const bf16x8*)(tc3 + plane + off);

        const float* sp = S + vp;
        union U { float f[4]; bf16x8 v; } b0, b1;
        b0.f[0]=sp[0];   b0.f[1]=sp[1];   b0.f[2]=sp[2];   b0.f[3]=sp[3];
        b1.f[0]=sp[136]; b1.f[1]=sp[137]; b1.f[2]=sp[138]; b1.f[3]=sp[139];

        a00 = MFMA16(h0, b0.v, a00,0,0,0);  a00 = MFMA16(l0, b0.v, a00,0,0,0);
        a10 = MFMA16(h1, b0.v, a10,0,0,0);  a10 = MFMA16(l1, b0.v, a10,0,0,0);
        a20 = MFMA16(h2, b0.v, a20,0,0,0);  a20 = MFMA16(l2, b0.v, a20,0,0,0);
        a30 = MFMA16(h3, b0.v, a30,0,0,0);  a30 = MFMA16(l3, b0.v, a30,0,0,0);
        a01 = MFMA16(h0, b1.v, a01,0,0,0);  a01 = MFMA16(l0, b1.v, a01,0,0,0);
        a11 = MFMA16(h1, b1.v, a11,0,0,0);  a11 = MFMA16(l1, b1.v, a11,0,0,0);
        a21 = MFMA16(h2, b1.v, a21,0,0,0);  a21 = MFMA16(l2, b1.v, a21,0,0,0);
        a31 = MFMA16(h3, b1.v, a31,0,0,0);  a31 = MFMA16(l3, b1.v, a31,0,0,0);

        h0=nh0; h1=nh1; h2=nh2; h3=nh3;
        l0=nl0; l1=nl1; l2=nl2; l3=nl3;
        vp -= 17;
    }

    const int j0 = jb + 512 * w + 16 * n + 4 * hib;   // multiple of 4
    float* y0 = out + (size_t)(c0 + 0) * NSAMP;
    float* y1 = out + (size_t)(c0 + 1) * NSAMP;
    float* y2 = out + (size_t)(c0 + 2) * NSAMP;
    float* y3 = out + (size_t)(c0 + 3) * NSAMP;
    if (j0 < NSAMP) {
        *(f32x4*)(y0 + j0) = a00; *(f32x4*)(y1 + j0) = a10;
        *(f32x4*)(y2 + j0) = a20; *(f32x4*)(y3 + j0) = a30;
    }
    if (j0 + 256 < NSAMP) {
        *(f32x4*)(y0 + j0 + 256) = a01; *(f32x4*)(y1 + j0 + 256) = a11;
        *(f32x4*)(y2 + j0 + 256) = a21; *(f32x4*)(y3 + j0 + 256) = a31;
    }
}

// ===========================================================================
// Per-channel 32x32x16 Toeplitz FIR (HP / env_f / env_bwd+gain).
// Block = 4096 outputs (4 waves x 1024), grid (54, channels).
// desc: B elem = x[jb'+32n+kap+17-16s]; asc: z[jb'+32n+16s+kap].
// phys16 swizzle: n-stride 17 dwords (odd) -> conflict-free.
// D: j = jb' + 32n + m, m = (reg&3)+8*(reg>>2)+4*(lane>>5).
// ===========================================================================
template<int NC, bool ASC, bool ABSIN, bool DELAYED, bool GAIN>
__global__ __launch_bounds__(BLOCK)
void fir32(const float* __restrict__ in, long instride,
           const unsigned short* __restrict__ TF,
           float* __restrict__ out,
           const int* __restrict__ delays, int chan0,
           const float* __restrict__ ratios, const float* __restrict__ eqloud)
{
    extern __shared__ float S[];
    unsigned* S32 = (unsigned*)S;
    const int c  = blockIdx.y;
    const int jb = blockIdx.x * 4096;
    const float* __restrict__ xin = in + (size_t)c * instride;
    const int o = ASC ? jb : (jb + 17 - 16 * (NC - 1));
    int d = 0;
    if (DELAYED) d = delays[chan0 + c];

    const int DW = 2040 + 8 * (NC - 1);   // (4080 + 16(NC-1))/2
    for (int v = threadIdx.x; v < DW; v += BLOCK) {
        int p0 = o + 2 * v, p1 = p0 + 1;
        float a = 0.f, b = 0.f;
        if (DELAYED) {
            if (p0 >= 0 && p0 + d < NSAMP) a = xin[p0 + d];
            if (p1 >= 0 && p1 + d < NSAMP) b = xin[p1 + d];
        } else {
            if (p0 >= 0 && p0 < NSAMP) a = xin[p0];
            if (p1 >= 0 && p1 < NSAMP) b = xin[p1];
        }
        if (ABSIN) { a = fabsf(a); b = fabsf(b); }
        S32[v + (v >> 4)] = (unsigned)f2bf(a) | ((unsigned)f2bf(b) << 16);
    }
    __syncthreads();

    const int lane = threadIdx.x & 63;
    const int w    = threadIdx.x >> 6;
    const int n    = lane & 31;
    const int h5   = lane >> 5;
    int v = 512 * w + 16 * n + 4 * h5 + (ASC ? 0 : 8 * (NC - 1));

    const unsigned short* tp = TF + (size_t)c * NC * 512 + lane * 8;

    f32x16 acc;
#pragma unroll
    for (int i = 0; i < 16; ++i) acc[i] = 0.f;
    bf16x8 A = *(const bf16x8*)tp;

#pragma unroll 1
    for (int s = 0; s < NC; ++s) {
        int sn = (s + 1 < NC) ? s + 1 : s;
        bf16x8 An = *(const bf16x8*)(tp + (size_t)sn * 512);
        int vp = v + (v >> 4);
        const float* sp = S + vp;
        union U { float f[4]; bf16x8 v; } B;
        B.f[0] = sp[0]; B.f[1] = sp[1]; B.f[2] = sp[2]; B.f[3] = sp[3];
        acc = MFMA32(A, B.v, acc, 0, 0, 0);
        A = An;
        v += ASC ? 8 : -8;
    }

    float* __restrict__ yo = out + (size_t)c * NSAMP;
    const int jbase = jb + 1024 * w + 32 * n + 4 * h5;   // multiple of 4
    if (!GAIN) {
#pragma unroll
        for (int g = 0; g < 4; ++g) {
            int j0 = jbase + 8 * g;
            if (j0 < NSAMP) {
                f32x4 st;
                st[0] = acc[4*g+0]; st[1] = acc[4*g+1];
                st[2] = acc[4*g+2]; st[3] = acc[4*g+3];
                *(f32x4*)(yo + j0) = st;
            }
        }
    } else {
        const float emax = exp10f(0.05f * (eqloud[c] - 100.0f));
        const float er   = fmaxf(ratios[c], -5.0f) - 1.0f;
#pragma unroll
        for (int g = 0; g < 4; ++g) {
            int j0 = jbase + 8 * g;
            if (j0 < NSAMP) {
                f32x4 pv = *(f32x4*)(yo + j0);
#pragma unroll
                for (int q = 0; q < 4; ++q) {
                    float env = acc[4*g+q];
                    float ecl = fminf(fmaxf(env, 1e-9f), emax);
                    float enr = fmaxf(ecl / emax, 1e-6f);
                    float gg  = fminf(powf(enr, er), 100.0f);
                    pv[q] *= gg;
                }
                *(f32x4*)(yo + j0) = pv;
            }
        }
    }
}

static inline size_t lds_gt4() { return (size_t)(3160 + (3160 >> 4) + 8) * 4; }
static inline size_t lds32(int NC)
{
    int DW = 2040 + 8 * (NC - 1);
    return (size_t)(DW + (DW >> 4) + 8) * 4;
}

// ===========================================================================
// VALU FIR (proven rounds 4-7) — tail chain only
// ===========================================================================
template<bool ASC>
__device__ __forceinline__ void group8r(const float (&LO)[8], const float (&HI)[8],
                                        float (&acc)[8], const f32x4 (&T)[2])
{
#pragma unroll
    for (int kp = 0; kp < 8; kp++) {
        const float hk = T[kp >> 2][kp & 3];
#pragma unroll
        for (int j = 0; j < 8; j++) {
            const int m = ASC ? (j + kp) : (8 + j - kp);
            const float w = (m < 8) ? LO[m] : HI[m - 8];
            acc[j] = fmaf(hk, w, acc[j]);
        }
    }
}

template<int Lpad, bool DELAYED>
__global__ __launch_bounds__(BLOCK)
void fir_blk(const float* __restrict__ in, long instride,
             const float* __restrict__ taps, int tapstride,
             float* __restrict__ out, long ostride,
             const int* __restrict__ delays, int chan0)
{
    extern __shared__ float s[];
    const int c  = blockIdx.y;
    const int n0 = blockIdx.x * TILE;
    const float* __restrict__ xin = in + (long)c * instride;
    float* __restrict__ y         = out + (long)c * ostride;
    int d = 0;
    if (DELAYED) d = delays[chan0 + c];

    constexpr int E = TILE + Lpad - 1;
    for (int i = threadIdx.x; i < E; i += BLOCK) {
        int p = n0 - (Lpad - 1) + i;
        float v = 0.f;
        if (p >= 0 && p < NSAMP) {
            int q = p + d;
            if (!DELAYED || q < NSAMP) v = xin[q];
        }
        s[phys9(i + 9)] = v;
    }
    __syncthreads();

    const int t = threadIdx.x;
    constexpr int LB = Lpad / 8;
    const int B = 9 * (t + LB);
    const f32x4* tv = (const f32x4*)(taps + (long)c * tapstride);

    float Ab[8], Bb[8], Cb[8];
    float acc[8] = {0,0,0,0,0,0,0,0};
#pragma unroll
    for (int m = 0; m < 8; m++) Ab[m] = s[B + m];
#pragma unroll
    for (int m = 0; m < 8; m++) Bb[m] = s[B + 9 + m];
    f32x4 TA[2], TB[2];
    TA[0] = tv[0]; TA[1] = tv[1];

    int Mb = B - 54;
    constexpr int NIT6 = Lpad / 48;
#pragma unroll 1
    for (int im = 0; im < NIT6; ++im) {
        const float* p = s + Mb;
#pragma unroll
        for (int m = 0; m < 8; m++) Cb[m] = p[45 + m];
        TB[0] = tv[2];  TB[1] = tv[3];
        group8r<false>(Ab, Bb, acc, TA);
#pragma unroll
        for (int m = 0; m < 8; m++) Bb[m] = p[36 + m];
        TA[0] = tv[4];  TA[1] = tv[5];
        group8r<false>(Cb, Ab, acc, TB);
#pragma unroll
        for (int m = 0; m < 8; m++) Ab[m] = p[27 + m];
        TB[0] = tv[6];  TB[1] = tv[7];
        group8r<false>(Bb, Cb, acc, TA);
#pragma unroll
        for (int m = 0; m < 8; m++) Cb[m] = p[18 + m];
        TA[0] = tv[8];  TA[1] = tv[9];
        group8r<false>(Ab, Bb, acc, TB);
#pragma unroll
        for (int m = 0; m < 8; m++) Bb[m] = p[9 + m];
        TB[0] = tv[10]; TB[1] = tv[11];
        group8r<false>(Cb, Ab, acc, TA);
#pragma unroll
        for (int m = 0; m < 8; m++) Ab[m] = p[0 + m];
        TA[0] = tv[12]; TA[1] = tv[13];
        group8r<false>(Bb, Cb, acc, TB);
        Mb -= 54;
        tv += 12;
    }

    const int nb = n0 + 8 * t;
#pragma unroll
    for (int j = 0; j < 8; j++)
        if (nb + j < NSAMP) y[nb + j] = acc[j];
}

static inline size_t lds_blk(int Lpad)
{
    int umax = TILE + Lpad + 8;
    return (size_t)(umax + (umax >> 3) + 16) * 4;
}

// ===========================================================================
// Small helpers
// ===========================================================================
// out[c,m] = sum_k a[c,k] a[c,m-k]; zeros for m in [Mlen, Mpad)
__global__ void conv_self(const float* __restrict__ a, int astride, int La,
                          float* __restrict__ out, int ostride, int Mlen, int Mpad)
{
    extern __shared__ float s[];
    const int c = blockIdx.y;
    const float* __restrict__ ar = a + (long)c * astride;
    for (int i = threadIdx.x; i < La; i += blockDim.x) s[i] = ar[i];
    __syncthreads();
    int m = blockIdx.x * blockDim.x + threadIdx.x;
    float acc = 0.f;
    for (int k = 0; k < La; k++) {
        int mi = m - k;
        float bv = ((unsigned)mi < (unsigned)La) ? s[mi] : 0.f;
        acc = fmaf(s[k], bv, acc);
    }
    if (m < Mpad) out[(long)c * ostride + m] = (m < Mlen) ? acc : 0.f;
}

// out[c,m] = sum_{k<Lb} b[k] * a[c, m-k]; zeros for m in [Mlen, Mpad)
__global__ void conv_pair(const float* __restrict__ a, int astride, int La,
                          const float* __restrict__ b, int Lb,
                          float* __restrict__ out, int ostride, int Mlen, int Mpad)
{
    extern __shared__ float s[];
    const int c = blockIdx.y;
    for (int i = threadIdx.x; i < Lb; i += blockDim.x) s[i] = b[i];
    __syncthreads();
    int m = blockIdx.x * blockDim.x + threadIdx.x;
    float acc = 0.f;
    for (int k = 0; k < Lb; k++) {
        int mi = m - k;
        float av = ((unsigned)mi < (unsigned)La) ? a[(size_t)c * astride + mi] : 0.f;
        acc = fmaf(s[k], av, acc);
    }
    if (m < Mpad) out[(size_t)c * ostride + m] = (m < Mlen) ? acc : 0.f;
}

__global__ void pad_copy(const float* __restrict__ src, int L, int sstride,
                         float* __restrict__ dst, int Lpad)
{
    int c = blockIdx.y;
    int k = blockIdx.x * blockDim.x + threadIdx.x;
    if (k < Lpad) dst[(long)c * Lpad + k] = (k < L) ? src[(long)c * sstride + k] : 0.f;
}

__global__ void delay_copy(const float* __restrict__ a, float* __restrict__ b,
                           const int* __restrict__ delays)
{
    int c = blockIdx.y;
    int n = blockIdx.x * blockDim.x + threadIdx.x;
    if (n < NSAMP) {
        int q = n + delays[c];
        b[(long)c * NSAMP + n] = (q < NSAMP) ? a[(long)c * NSAMP + q] : 0.f;
    }
}

__global__ void reduce_coch(const float* __restrict__ b, float* __restrict__ coch)
{
    int n = blockIdx.x * blockDim.x + threadIdx.x;
    if (n < NSAMP) {
        float sum = 0.f;
        for (int c = 0; c < NCH; c++) sum += b[(long)c * NSAMP + n];
        coch[n] = sum * 0.31622776601683794f;
    }
}

extern "C" void kernel_launch(void* const* d_in, const int* in_sizes, int n_in,
                              void* d_out, int out_size, void* d_ws, size_t ws_size,
                              hipStream_t stream)
{
    const float* x       = (const float*)d_in[0];
    const float* src_fwd = (const float*)d_in[1];
    const float* src_bwd = (const float*)d_in[2];
    const float* lpf     = (const float*)d_in[3];
    const float* gtn     = (const float*)d_in[4];  // [28,1000]
    const float* hp      = (const float*)d_in[5];  // [24,1000]
    const float* clpf    = (const float*)d_in[6];  // [28,2000]
    const float* ratios  = (const float*)d_in[7];
    const float* eqloud  = (const float*)d_in[8];
    const int*   delays  = (const int*)d_in[9];
    float* out = (float*)d_out;

    float* ws = (float*)d_ws;
    const size_t CNs = (size_t)NCH * NSAMP;
    float* bufA  = ws;                            // C*N (y4, then env_f)
    float* bufB  = bufA + CNs;                    // C*N (pass_del -> coch_c)
    float* coch  = bufB + CNs;                    // N
    float* h2    = coch + NSAMP;                  // 28*2000
    float* h4    = h2 + (size_t)NCH * 2000;       // 28*LP_GT4
    float* h4f   = h4 + (size_t)NCH * LP_GT4;     // 28*LP_H4F (src_fwd folded)
    float* hpP   = h4f + (size_t)NCH * LP_H4F;    // 24*LP_HP
    float* clpfP = hpP + (size_t)HPCH * LP_HP;    // 28*LP_ENV
    float* tb    = clpfP + (size_t)NCH * LP_ENV;  // LP_TB (lpf (*) src_bwd)

    unsigned short* TFgt = (unsigned short*)(tb + LP_TB);
    const long gtPlane = (long)NCH * NC_GT * 512;
    unsigned short* TFhp = TFgt + 2 * gtPlane;
    unsigned short* TFef = TFhp + (size_t)HPCH * NC_HP * 512;
    unsigned short* TFeb = TFef + (size_t)NCH * NC_EF * 512;

    dim3 blk(BLOCK);

    // --- filter prep ---
    conv_self<<<dim3(8, NCH), blk, 1000 * 4, stream>>>(
        gtn, 1000, 1000, h2, 2000, 1999, 1999);
    conv_self<<<dim3(16, NCH), blk, 1999 * 4, stream>>>(
        h2, 2000, 1999, h4, LP_GT4, 3997, LP_GT4);
    // h4f = src_fwd (*) h4  (front correction folded into gammatone taps)
    conv_pair<<<dim3((LP_H4F + BLOCK - 1) / BLOCK, NCH), blk, 256 * 4, stream>>>(
        h4, LP_GT4, 3997, src_fwd, 256, h4f, LP_H4F, L_H4F, LP_H4F);
    // tb = lpf (*) src_bwd (tail corrections fused into one FIR)
    conv_pair<<<dim3(2, 1), blk, 133 * 4, stream>>>(
        src_bwd, 0, 256, lpf, 133, tb, LP_TB, L_TB, LP_TB);
    pad_copy<<<dim3(4, HPCH), blk, 0, stream>>>(hp, 1000, 1000, hpP, LP_HP);
    pad_copy<<<dim3(8, NCH), blk, 0, stream>>>(clpf, 2000, 2000, clpfP, LP_ENV);

    prep_frag<<<dim3(NC_GT, NCH), dim3(64), 0, stream>>>(
        h4f, LP_H4F, TFgt, NC_GT, 0, 1, gtPlane);
    prep_frag32<<<dim3(NC_HP, HPCH), dim3(64), 0, stream>>>(
        hpP, LP_HP, TFhp, NC_HP, 0);
    prep_frag32<<<dim3(NC_EF, NCH), dim3(64), 0, stream>>>(
        clpfP, LP_ENV, TFef, NC_EF, 0);
    prep_frag32<<<dim3(NC_EB, NCH), dim3(64), 0, stream>>>(
        clpfP, LP_ENV, TFeb, NC_EB, 1);

    // --- signal path ---
    // y4 = (gammatone^4 (*) src_fwd) applied to x; 4 channels/block
    gt4_mfma4<<<dim3(108, 7), blk, lds_gt4(), stream>>>(x, TFgt, gtPlane, bufA);

    // pass_del ch 0..3: delayed copy
    delay_copy<<<dim3((NSAMP + BLOCK - 1) / BLOCK, 4), blk, 0, stream>>>(
        bufA, bufB, delays);

    // pass_del ch 4..27: HP with delay fetched at staging
    fir32<NC_HP, false, false, true, false>
        <<<dim3(54, HPCH), blk, lds32(NC_HP), stream>>>(
        bufA + 4 * (size_t)NSAMP, NSAMP, TFhp, bufB + 4 * (size_t)NSAMP,
        delays, 4, nullptr, nullptr);

    // env_f = causal fir(|pass_del|, clpf)
    fir32<NC_EF, false, true, false, false>
        <<<dim3(54, NCH), blk, lds32(NC_EF), stream>>>(
        bufB, NSAMP, TFef, bufA, nullptr, 0, nullptr, nullptr);

    // env = anti-causal fir(|env_f|, clpf) + fused recruitment gain
    fir32<NC_EB, true, true, false, true>
        <<<dim3(54, NCH), blk, lds32(NC_EB), stream>>>(
        bufA, NSAMP, TFeb, bufB, nullptr, 0, ratios, eqloud);

    // coch = 10^-0.5 * sum_c coch_c
    reduce_coch<<<dim3((NSAMP + BLOCK - 1) / BLOCK), blk, 0, stream>>>(bufB, coch);

    // out = (lpf (*) src_bwd) (*) coch  — single fused tail FIR
    fir_blk<LP_TB, false><<<dim3(108, 1), blk, lds_blk(LP_TB), stream>>>(
        coch, 0, tb, LP_TB, out, 0, nullptr, 0);
}